// Round 9
// baseline (451.510 us; speedup 1.0000x reference)
//
#include <hip/hip_runtime.h>

typedef unsigned short u16;
typedef __attribute__((ext_vector_type(8))) short short8;
typedef __attribute__((ext_vector_type(4))) float f32x4;
typedef __attribute__((ext_vector_type(4))) unsigned int u32x4;
typedef __attribute__((ext_vector_type(4))) unsigned short u16x4;

#define LOG2E 1.4426950408889634f

__device__ __forceinline__ float bf2f(u16 u) {
    union { float f; unsigned int i; } c; c.i = ((unsigned int)u) << 16; return c.f;
}
__device__ __forceinline__ u16 f2bf(float f) {
    unsigned int x = __float_as_uint(f);
    x += 0x7fff + ((x >> 16) & 1);   // RNE
    return (u16)(x >> 16);
}
// packed f32 pair -> 2x bf16 in one VALU op (RNE, gfx950)
__device__ __forceinline__ unsigned int cvtpk(float lo, float hi) {
    unsigned int d;
    asm("v_cvt_pk_bf16_f32 %0, %1, %2" : "=v"(d) : "v"(lo), "v"(hi));
    return d;
}

union Cvt32 { u32x4 v[4]; u16 u[32]; };

// load 32 consecutive fp32 and convert to 32 bf16 (cvtpk: 16 VALU ops)
__device__ __forceinline__ void ld32f_bf(const float* __restrict__ p, Cvt32& t) {
    union { unsigned int i[8]; u32x4 v[2]; } a;
#pragma unroll
    for (int j = 0; j < 4; j++) {
        f32x4 x = *(const f32x4*)(p + j * 4);
        a.i[j * 2]     = cvtpk(x[0], x[1]);
        a.i[j * 2 + 1] = cvtpk(x[2], x[3]);
    }
    t.v[0] = a.v[0]; t.v[1] = a.v[1];
#pragma unroll
    for (int j = 0; j < 4; j++) {
        f32x4 x = *(const f32x4*)(p + 16 + j * 4);
        a.i[j * 2]     = cvtpk(x[0], x[1]);
        a.i[j * 2 + 1] = cvtpk(x[2], x[3]);
    }
    t.v[2] = a.v[0]; t.v[3] = a.v[1];
}

// ===========================================================================
// ============================ PATH A (large ws) ============================
// ===========================================================================

// Prep: proj weights -> wt (per-head [half][h][n][k] layout, n<32 = K/Q,
// n>=32 = V/G), output_w -> WoT[o][hc], nb -> nbT[h][k][q]*LOG2E bf16.
__global__ __launch_bounds__(256) void prep_a(
    const float* __restrict__ nb,
    const float* __restrict__ qw, const float* __restrict__ kw,
    const float* __restrict__ vw, const float* __restrict__ gw,
    const float* __restrict__ ow,
    u16* __restrict__ wt, u16* __restrict__ WoT, u16* __restrict__ nbT)
{
    __shared__ float tile[64][65];
    int blk = blockIdx.x, tid = threadIdx.x;
    if (blk < 1024) {
        int i = blk * 256 + tid;             // 0..262143
        int half = i >> 17;
        int rem = i & 131071;
        int h = rem >> 14, e = rem & 16383;
        int n = e >> 8, k = e & 255;
        int src_idx = k * 256 + h * 32 + (n & 31);
        float v;
        if (half == 0) v = (n < 32) ? kw[src_idx] : vw[src_idx];
        else           v = (n < 32) ? qw[src_idx] : gw[src_idx];
        wt[i] = f2bf(v);
    } else if (blk < 1280) {
        int e = (blk - 1024) * 256 + tid;    // 0..65535
        int o = e & 255, hc = e >> 8;
        WoT[o * 256 + hc] = f2bf(ow[hc * 256 + o]);
    } else {
        int idx = blk - 1280;                // 0..127
        int q0 = (idx & 3) * 64, k0 = ((idx >> 2) & 3) * 64, h = idx >> 4;
        int rr = tid >> 4;                   // 0..15
        int cc = (tid & 15) << 2;            // 0,4,..,60
        const float* src = nb + ((size_t)(h * 256 + q0)) * 256 + k0;
#pragma unroll
        for (int p = 0; p < 4; p++) {
            int q = rr + p * 16;
            f32x4 x = *(const f32x4*)(src + (size_t)q * 256 + cc);
            tile[q][cc] = x[0]; tile[q][cc + 1] = x[1];
            tile[q][cc + 2] = x[2]; tile[q][cc + 3] = x[3];
        }
        __syncthreads();
        u16* dst = nbT + ((size_t)(h * 256 + k0)) * 256 + q0;
#pragma unroll
        for (int p = 0; p < 4; p++) {
            int k = rr + p * 16;
            u16x4 o;
#pragma unroll
            for (int u = 0; u < 4; u++) o[u] = f2bf(tile[cc + u][k] * LOG2E);
            *(u16x4*)(dst + (size_t)k * 256 + cc) = o;
        }
    }
}

// Fused projection + attention per (b,h). Round-9: (1) phase order swapped
// (Q/G -> regs FIRST, then K/V) so the X staging buffer and Ksh share one
// LDS region (Xs dies exactly when K is produced; each wave touches only
// its own 64-row band, so the in-place handoff needs no extra barrier) —
// LDS 62,976 -> 51,712 B -> 3 blocks/CU; (2) coalesced staging: 2 threads
// per row (64 B contiguous each), wave covers 32 rows of 128-B segments,
// replacing the 1KB-strided row-per-thread scatter loads (r8 counter
// evidence: 23% occupancy, uncoalesced VMEM issue).
__global__ __launch_bounds__(256, 3) void fusedA(
    const float* __restrict__ q_data, const float* __restrict__ m_data,
    const float* __restrict__ bias2, const u16* __restrict__ nbT,
    const u16* __restrict__ wt, const float* __restrict__ gb,
    u16* __restrict__ WA)
{
    __shared__ u16 smem[25856];          // 51,712 B
    u16* Vt  = smem;                     // [32][264]   8,448 u16
    u16* Xs  = smem + 8448;              // [256][40]  10,240 u16 -> becomes Ksh
    u16* Ksh = Xs;                       //   (aliased: K written in-place)
    u16* Wsh = smem + 18688;             // [64][40]    2,560 u16 (proj only)

    int bid = blockIdx.x;
    int b = bid >> 3, h = bid & 7;
    int tid = threadIdx.x, lane = tid & 63, w = tid >> 6;
    int l15 = lane & 15;
    int kl = (lane >> 4) << 3;
    int rq = (lane >> 4) << 2;
    const f32x4 fz = {0.f, 0.f, 0.f, 0.f};

    float bload[16];
#pragma unroll
    for (int t = 0; t < 16; t++)
        bload[t] = bias2[(b << 8) + t * 16 + l15] * LOG2E;
    float gbc0 = gb[h * 32 + l15];
    float gbc1 = gb[h * 32 + 16 + l15];

    int srow = tid >> 1;                 // 0..127 (staging row within pass)
    int sc16 = (tid & 1) << 4;           // f32 col 0 / 16
    int nrow = tid >> 1, nc = (tid & 1) << 4;

    // ---------- phase 1: Q,G projection (X = q_data[b]) -> acc2 regs --------
    const float* Xg2 = q_data + ((size_t)b << 16);
    const u16* Wg2 = wt + 131072 + (h << 14);
    f32x4 acc2[4][4];
#pragma unroll
    for (int i = 0; i < 4; i++)
#pragma unroll
        for (int j = 0; j < 4; j++) acc2[i][j] = fz;

    for (int kb = 0; kb < 8; ++kb) {
        // coalesced A-stage: 2 passes x (2 thr/row x 128 rows), 64B/thread
        u32x4 c0[2], c1[2];
#pragma unroll
        for (int p = 0; p < 2; ++p) {
            const float* ps = Xg2 + (size_t)(p * 128 + srow) * 256 + kb * 32 + sc16;
            f32x4 x0 = *(const f32x4*)ps;
            f32x4 x1 = *(const f32x4*)(ps + 4);
            f32x4 x2 = *(const f32x4*)(ps + 8);
            f32x4 x3 = *(const f32x4*)(ps + 12);
            union { unsigned int i4[4]; u32x4 v; } a, c;
            a.i4[0] = cvtpk(x0[0], x0[1]); a.i4[1] = cvtpk(x0[2], x0[3]);
            a.i4[2] = cvtpk(x1[0], x1[1]); a.i4[3] = cvtpk(x1[2], x1[3]);
            c.i4[0] = cvtpk(x2[0], x2[1]); c.i4[1] = cvtpk(x2[2], x2[3]);
            c.i4[2] = cvtpk(x3[0], x3[1]); c.i4[3] = cvtpk(x3[2], x3[3]);
            c0[p] = a.v; c1[p] = c.v;
        }
        u32x4 b0, b1;
        if (tid < 128) {
            const u16* q = Wg2 + nrow * 256 + kb * 32 + nc;
            b0 = *(const u32x4*)q; b1 = *(const u32x4*)(q + 8);
        }
        if (kb) __syncthreads();
#pragma unroll
        for (int p = 0; p < 2; ++p) {
            int row = p * 128 + srow;
            *(u32x4*)&Xs[row * 40 + sc16]     = c0[p];
            *(u32x4*)&Xs[row * 40 + sc16 + 8] = c1[p];
        }
        if (tid < 128) {
            *(u32x4*)&Wsh[nrow * 40 + nc] = b0;
            *(u32x4*)&Wsh[nrow * 40 + nc + 8] = b1;
        }
        __syncthreads();
        short8 af[4], bf[4];
#pragma unroll
        for (int i = 0; i < 4; i++) af[i] = *(const short8*)&Xs[(64 * w + i * 16 + l15) * 40 + kl];
#pragma unroll
        for (int i = 0; i < 4; i++) bf[i] = *(const short8*)&Wsh[(i * 16 + l15) * 40 + kl];
#pragma unroll
        for (int mi = 0; mi < 4; mi++)
#pragma unroll
            for (int ni = 0; ni < 4; ni++)
                acc2[mi][ni] = __builtin_amdgcn_mfma_f32_16x16x32_bf16(af[mi], bf[ni], acc2[mi][ni], 0, 0, 0);
    }

    // ---------- phase 2: K,V projection (X = m_data[b]) -> Ksh(=Xs), Vt -----
    const float* Xg = m_data + ((size_t)b << 16);
    const u16* Wg = wt + (h << 14);
    f32x4 acc[4][4];
#pragma unroll
    for (int i = 0; i < 4; i++)
#pragma unroll
        for (int j = 0; j < 4; j++) acc[i][j] = fz;

    for (int kb = 0; kb < 8; ++kb) {
        u32x4 c0[2], c1[2];
#pragma unroll
        for (int p = 0; p < 2; ++p) {
            const float* ps = Xg + (size_t)(p * 128 + srow) * 256 + kb * 32 + sc16;
            f32x4 x0 = *(const f32x4*)ps;
            f32x4 x1 = *(const f32x4*)(ps + 4);
            f32x4 x2 = *(const f32x4*)(ps + 8);
            f32x4 x3 = *(const f32x4*)(ps + 12);
            union { unsigned int i4[4]; u32x4 v; } a, c;
            a.i4[0] = cvtpk(x0[0], x0[1]); a.i4[1] = cvtpk(x0[2], x0[3]);
            a.i4[2] = cvtpk(x1[0], x1[1]); a.i4[3] = cvtpk(x1[2], x1[3]);
            c.i4[0] = cvtpk(x2[0], x2[1]); c.i4[1] = cvtpk(x2[2], x2[3]);
            c.i4[2] = cvtpk(x3[0], x3[1]); c.i4[3] = cvtpk(x3[2], x3[3]);
            c0[p] = a.v; c1[p] = c.v;
        }
        u32x4 b0, b1;
        if (tid < 128) {
            const u16* q = Wg + nrow * 256 + kb * 32 + nc;
            b0 = *(const u32x4*)q; b1 = *(const u32x4*)(q + 8);
        }
        __syncthreads();   // unconditional: protects phase-1 reads at kb=0
#pragma unroll
        for (int p = 0; p < 2; ++p) {
            int row = p * 128 + srow;
            *(u32x4*)&Xs[row * 40 + sc16]     = c0[p];
            *(u32x4*)&Xs[row * 40 + sc16 + 8] = c1[p];
        }
        if (tid < 128) {
            *(u32x4*)&Wsh[nrow * 40 + nc] = b0;
            *(u32x4*)&Wsh[nrow * 40 + nc + 8] = b1;
        }
        __syncthreads();
        short8 af[4], bf[4];
#pragma unroll
        for (int i = 0; i < 4; i++) af[i] = *(const short8*)&Xs[(64 * w + i * 16 + l15) * 40 + kl];
#pragma unroll
        for (int i = 0; i < 4; i++) bf[i] = *(const short8*)&Wsh[(i * 16 + l15) * 40 + kl];
#pragma unroll
        for (int mi = 0; mi < 4; mi++)
#pragma unroll
            for (int ni = 0; ni < 4; ni++)
                acc[mi][ni] = __builtin_amdgcn_mfma_f32_16x16x32_bf16(af[mi], bf[ni], acc[mi][ni], 0, 0, 0);
    }
    // epilogue: K into Ksh (in-place over this wave's own Xs band), V -> Vt
#pragma unroll
    for (int mi = 0; mi < 4; mi++)
#pragma unroll
        for (int ni = 0; ni < 4; ni++)
#pragma unroll
            for (int r = 0; r < 4; r++) {
                int s = 64 * w + mi * 16 + rq + r;
                int col = ni * 16 + l15;
                u16 v = f2bf(acc[mi][ni][r]);
                if (ni < 2) Ksh[s * 40 + col] = v;
                else        Vt[(col - 32) * 264 + s] = v;
            }
    __syncthreads();

    // ---------- phase 3: attention (fully unrolled mt — static acc2 idx) ----
    u16* myQ = smem + 18688 + w * 1792;  // per-wave: [16][40] (overlays Wsh+)
    u16* myP = myQ + 640;                // per-wave: [16][72]
    const u16* nbh = nbT + ((size_t)h << 16);
    const float qs = 0.17677669529663687f * LOG2E;
    int orow = lane >> 2, ocol = (lane & 3) << 3;

#pragma unroll
    for (int mt = 0; mt < 4; ++mt) {
        int q0 = 64 * w + mt * 16 + rq;
#pragma unroll
        for (int ni = 0; ni < 2; ++ni)
#pragma unroll
            for (int r = 0; r < 4; r++)
                myQ[(rq + r) * 40 + ni * 16 + l15] = f2bf(acc2[mt][ni][r] * qs);
        short8 qf = *(const short8*)&myQ[l15 * 40 + kl];

        const u16* nbp = nbh + q0;
        float srow_[4] = {0.f, 0.f, 0.f, 0.f};
        f32x4 oacc[2] = {fz, fz};
#pragma unroll
        for (int qt = 0; qt < 4; ++qt) {
            f32x4 sc[4];
#pragma unroll
            for (int t = 0; t < 4; t++) {
                int tt = qt * 4 + t;
                short8 kfr = *(const short8*)&Ksh[(tt * 16 + l15) * 40 + kl];
                f32x4 cb = {bload[tt], bload[tt], bload[tt], bload[tt]};
                sc[t] = __builtin_amdgcn_mfma_f32_16x16x32_bf16(qf, kfr, cb, 0, 0, 0);
            }
#pragma unroll
            for (int t = 0; t < 4; t++) {
                int tt = qt * 4 + t;
                u16x4 nbv = *(const u16x4*)(nbp + ((tt * 16 + l15) << 8));
#pragma unroll
                for (int r = 0; r < 4; r++) {
                    // no-max softmax in exp2 domain (|logit*log2e| << 127)
                    float p = __builtin_amdgcn_exp2f(sc[t][r] + bf2f(nbv[r]));
                    srow_[r] += p;
                    myP[(rq + r) * 72 + t * 16 + l15] = f2bf(p);
                }
            }
#pragma unroll
            for (int ks = 0; ks < 2; ++ks) {
                short8 pf = *(const short8*)&myP[l15 * 72 + ks * 32 + kl];
#pragma unroll
                for (int ni = 0; ni < 2; ++ni) {
                    short8 vf = *(const short8*)&Vt[(ni * 16 + l15) * 264 + qt * 64 + ks * 32 + kl];
                    oacc[ni] = __builtin_amdgcn_mfma_f32_16x16x32_bf16(pf, vf, oacc[ni], 0, 0, 0);
                }
            }
        }
#pragma unroll
        for (int r = 0; r < 4; r++) {
            float s = srow_[r];
            s += __shfl_xor(s, 1);
            s += __shfl_xor(s, 2);
            s += __shfl_xor(s, 4);
            s += __shfl_xor(s, 8);
            srow_[r] = __builtin_amdgcn_rcpf(s);
        }

        // gate from live acc2 (static mt), normalize, stage
#pragma unroll
        for (int ni = 0; ni < 2; ++ni) {
            float gbv = ni ? gbc1 : gbc0;
#pragma unroll
            for (int r = 0; r < 4; r++) {
                float gate = __builtin_amdgcn_rcpf(
                    1.f + __builtin_amdgcn_exp2f(-(acc2[mt][ni + 2][r] + gbv) * LOG2E));
                myP[(rq + r) * 40 + ni * 16 + l15] = f2bf(oacc[ni][r] * srow_[r] * gate);
            }
        }
        // coalesced store: WA[(b*256+q)][h*32+c], 16B/lane
        u32x4 ov = *(const u32x4*)&myP[orow * 40 + ocol];
        *(u32x4*)(WA + ((size_t)((b << 8) + 64 * w + mt * 16 + orow) << 8) + h * 32 + ocol) = ov;
    }
}

// Output GEMM: out[65536,256] = WA[65536,256](bf16) @ WoT^T + output_b.
__global__ __launch_bounds__(256) void gemmout_a(
    const u16* __restrict__ WA, const u16* __restrict__ WoT,
    float* __restrict__ dst, const float* __restrict__ ob)
{
    __shared__ u16 As[128 * 40];
    __shared__ u16 Bs[128 * 40];
    int tid = threadIdx.x;
    int lane = tid & 63, w = tid >> 6;
    int wm = w >> 1, wn = w & 1;
    int row0 = blockIdx.x * 128;
    int n0 = blockIdx.y * 128;
    int lr = tid >> 1;
    int lc = (tid & 1) << 4;

    const f32x4 fz = {0.f, 0.f, 0.f, 0.f};
    f32x4 acc[4][4];
#pragma unroll
    for (int i = 0; i < 4; i++)
#pragma unroll
        for (int j = 0; j < 4; j++) acc[i][j] = fz;

    int kl = (lane >> 4) << 3;
    int l15 = lane & 15;
    int rm = wm * 64 + l15;
    int rn = wn * 64 + l15;

    for (int kb = 0; kb < 8; ++kb) {
        int k0 = kb << 5;
        const u16* pa = WA + ((size_t)(row0 + lr) << 8) + k0 + lc;
        u32x4 a0 = *(const u32x4*)pa;
        u32x4 a1 = *(const u32x4*)(pa + 8);
        const u16* pb = WoT + ((size_t)(n0 + lr) << 8) + k0 + lc;
        u32x4 b0 = *(const u32x4*)pb;
        u32x4 b1 = *(const u32x4*)(pb + 8);
        if (kb) __syncthreads();
        *(u32x4*)&As[lr * 40 + lc] = a0;
        *(u32x4*)&As[lr * 40 + lc + 8] = a1;
        *(u32x4*)&Bs[lr * 40 + lc] = b0;
        *(u32x4*)&Bs[lr * 40 + lc + 8] = b1;
        __syncthreads();
        short8 af[4], bf[4];
#pragma unroll
        for (int i = 0; i < 4; i++) af[i] = *(const short8*)&As[(rm + i * 16) * 40 + kl];
#pragma unroll
        for (int i = 0; i < 4; i++) bf[i] = *(const short8*)&Bs[(rn + i * 16) * 40 + kl];
#pragma unroll
        for (int mi = 0; mi < 4; mi++)
#pragma unroll
            for (int ni = 0; ni < 4; ni++)
                acc[mi][ni] = __builtin_amdgcn_mfma_f32_16x16x32_bf16(af[mi], bf[ni], acc[mi][ni], 0, 0, 0);
    }

#pragma unroll
    for (int mi = 0; mi < 4; mi++)
#pragma unroll
        for (int ni = 0; ni < 4; ni++)
#pragma unroll
            for (int r = 0; r < 4; r++) {
                int row = row0 + wm * 64 + mi * 16 + ((lane >> 4) << 2) + r;
                int col = n0 + wn * 64 + ni * 16 + l15;
                dst[((size_t)row << 8) + col] = acc[mi][ni][r] + ob[col];
            }
}

// ===========================================================================
// ===================== PATH B (small ws) — round-4 code ====================
// ===========================================================================

__global__ __launch_bounds__(256) void transpose_k(
    const float* __restrict__ query_w, const float* __restrict__ key_w,
    const float* __restrict__ value_w, const float* __restrict__ gating_w,
    u16* __restrict__ wt)
{
    int i = blockIdx.x * 256 + threadIdx.x;
    int half = i >> 17;
    int rem = i & 131071;
    int h = rem >> 14, e = rem & 16383;
    int n = e >> 8, k = e & 255;
    int src_idx = k * 256 + h * 32 + (n & 31);
    float v;
    if (half == 0) v = (n < 32) ? key_w[src_idx]   : value_w[src_idx];
    else           v = (n < 32) ? query_w[src_idx] : gating_w[src_idx];
    wt[i] = f2bf(v);
}

__global__ __launch_bounds__(256) void fused_attn_k(
    const float* __restrict__ q_data, const float* __restrict__ m_data,
    const float* __restrict__ bias2, const float* __restrict__ nb,
    const u16* __restrict__ wt, const float* __restrict__ gb,
    u16* __restrict__ WAo)
{
    __shared__ u16 smem[31488];
    u16* Ksh = smem;
    u16* Vt  = smem + 10240;
    u16* Xs  = smem + 18688;
    u16* Wsh = smem + 28928;

    int bid = blockIdx.x;
    int b = bid >> 3, h = bid & 7;
    int tid = threadIdx.x, lane = tid & 63, w = tid >> 6;
    int l15 = lane & 15;
    int kl = (lane >> 4) << 3;
    int rq = (lane >> 4) << 2;
    const f32x4 fz = {0.f, 0.f, 0.f, 0.f};

    float bload[16];
#pragma unroll
    for (int t = 0; t < 16; t++) bload[t] = bias2[(b << 8) + t * 16 + l15];
    float gbc0 = gb[h * 32 + l15];
    float gbc1 = gb[h * 32 + 16 + l15];

    const float* Xg = m_data + ((size_t)b << 16);
    const u16* Wg = wt + (h << 14);
    f32x4 acc[4][4];
#pragma unroll
    for (int i = 0; i < 4; i++)
#pragma unroll
        for (int j = 0; j < 4; j++) acc[i][j] = fz;

    for (int kb = 0; kb < 8; ++kb) {
        Cvt32 am;
        ld32f_bf(Xg + (size_t)tid * 256 + kb * 32, am);
        u32x4 b0, b1;
        int nrow = tid >> 1, nc = (tid & 1) << 4;
        if (tid < 128) {
            const u16* q = Wg + nrow * 256 + kb * 32 + nc;
            b0 = *(const u32x4*)q; b1 = *(const u32x4*)(q + 8);
        }
        if (kb) __syncthreads();
        *(u32x4*)&Xs[tid * 40]      = am.v[0];
        *(u32x4*)&Xs[tid * 40 + 8]  = am.v[1];
        *(u32x4*)&Xs[tid * 40 + 16] = am.v[2];
        *(u32x4*)&Xs[tid * 40 + 24] = am.v[3];
        if (tid < 128) {
            *(u32x4*)&Wsh[nrow * 40 + nc] = b0;
            *(u32x4*)&Wsh[nrow * 40 + nc + 8] = b1;
        }
        __syncthreads();
        short8 af[4], bf[4];
#pragma unroll
        for (int i = 0; i < 4; i++) af[i] = *(const short8*)&Xs[(64 * w + i * 16 + l15) * 40 + kl];
#pragma unroll
        for (int i = 0; i < 4; i++) bf[i] = *(const short8*)&Wsh[(i * 16 + l15) * 40 + kl];
#pragma unroll
        for (int mi = 0; mi < 4; mi++)
#pragma unroll
            for (int ni = 0; ni < 4; ni++)
                acc[mi][ni] = __builtin_amdgcn_mfma_f32_16x16x32_bf16(af[mi], bf[ni], acc[mi][ni], 0, 0, 0);
    }
#pragma unroll
    for (int mi = 0; mi < 4; mi++)
#pragma unroll
        for (int ni = 0; ni < 4; ni++)
#pragma unroll
            for (int r = 0; r < 4; r++) {
                int s = 64 * w + mi * 16 + rq + r;
                int col = ni * 16 + l15;
                u16 v = f2bf(acc[mi][ni][r]);
                if (ni < 2) Ksh[s * 40 + col] = v;
                else        Vt[(col - 32) * 264 + s] = v;
            }
    __syncthreads();

    const float* Xg2 = q_data + ((size_t)b << 16);
    const u16* Wg2 = wt + 131072 + (h << 14);
    f32x4 acc2[4][4];
#pragma unroll
    for (int i = 0; i < 4; i++)
#pragma unroll
        for (int j = 0; j < 4; j++) acc2[i][j] = fz;

    for (int kb = 0; kb < 8; ++kb) {
        Cvt32 am;
        ld32f_bf(Xg2 + (size_t)tid * 256 + kb * 32, am);
        u32x4 b0, b1;
        int nrow = tid >> 1, nc = (tid & 1) << 4;
        if (tid < 128) {
            const u16* q = Wg2 + nrow * 256 + kb * 32 + nc;
            b0 = *(const u32x4*)q; b1 = *(const u32x4*)(q + 8);
        }
        __syncthreads();
        *(u32x4*)&Xs[tid * 40]      = am.v[0];
        *(u32x4*)&Xs[tid * 40 + 8]  = am.v[1];
        *(u32x4*)&Xs[tid * 40 + 16] = am.v[2];
        *(u32x4*)&Xs[tid * 40 + 24] = am.v[3];
        if (tid < 128) {
            *(u32x4*)&Wsh[nrow * 40 + nc] = b0;
            *(u32x4*)&Wsh[nrow * 40 + nc + 8] = b1;
        }
        __syncthreads();
        short8 af[4], bf[4];
#pragma unroll
        for (int i = 0; i < 4; i++) af[i] = *(const short8*)&Xs[(64 * w + i * 16 + l15) * 40 + kl];
#pragma unroll
        for (int i = 0; i < 4; i++) bf[i] = *(const short8*)&Wsh[(i * 16 + l15) * 40 + kl];
#pragma unroll
        for (int mi = 0; mi < 4; mi++)
#pragma unroll
            for (int ni = 0; ni < 4; ni++)
                acc2[mi][ni] = __builtin_amdgcn_mfma_f32_16x16x32_bf16(af[mi], bf[ni], acc2[mi][ni], 0, 0, 0);
    }
    __syncthreads();

    u16* myQ = smem + 18688 + w * 2816;
    u16* myP = myQ + 640;
    const float* nbp = nb + ((size_t)h << 16);
    const float qscale = 0.17677669529663687f;

#pragma unroll
    for (int mt = 0; mt < 4; ++mt) {
#pragma unroll
        for (int ni = 0; ni < 2; ++ni)
#pragma unroll
            for (int r = 0; r < 4; r++)
                myQ[(rq + r) * 40 + ni * 16 + l15] = f2bf(acc2[mt][ni][r] * qscale);

        short8 qf = *(const short8*)&myQ[l15 * 40 + kl];
        f32x4 sc[16];
#pragma unroll
        for (int t = 0; t < 16; t++) {
            short8 kfr = *(const short8*)&Ksh[(t * 16 + l15) * 40 + kl];
            sc[t] = __builtin_amdgcn_mfma_f32_16x16x32_bf16(qf, kfr, fz, 0, 0, 0);
        }

        int q0 = 64 * w + mt * 16 + rq;
        float mrow[4] = {-3e30f, -3e30f, -3e30f, -3e30f};
#pragma unroll
        for (int t = 0; t < 16; t++) {
            int kidx = t * 16 + l15;
#pragma unroll
            for (int r = 0; r < 4; r++) {
                float v = sc[t][r] + bload[t] + nbp[(size_t)(q0 + r) * 256 + kidx];
                sc[t][r] = v;
                mrow[r] = fmaxf(mrow[r], v);
            }
        }
#pragma unroll
        for (int r = 0; r < 4; r++) {
            float m = mrow[r];
            m = fmaxf(m, __shfl_xor(m, 1));
            m = fmaxf(m, __shfl_xor(m, 2));
            m = fmaxf(m, __shfl_xor(m, 4));
            m = fmaxf(m, __shfl_xor(m, 8));
            mrow[r] = m;
        }
        float srow[4] = {0.f, 0.f, 0.f, 0.f};
#pragma unroll
        for (int t = 0; t < 16; t++)
#pragma unroll
            for (int r = 0; r < 4; r++) {
                float p = __expf(sc[t][r] - mrow[r]);
                sc[t][r] = p;
                srow[r] += p;
            }
#pragma unroll
        for (int r = 0; r < 4; r++) {
            float s = srow[r];
            s += __shfl_xor(s, 1);
            s += __shfl_xor(s, 2);
            s += __shfl_xor(s, 4);
            s += __shfl_xor(s, 8);
            srow[r] = 1.f / s;
        }

        f32x4 oacc[2] = {fz, fz};
#pragma unroll
        for (int half = 0; half < 2; ++half) {
#pragma unroll
            for (int t = 0; t < 8; t++)
#pragma unroll
                for (int r = 0; r < 4; r++)
                    myP[(rq + r) * 136 + t * 16 + l15] =
                        f2bf(sc[half * 8 + t][r] * srow[r]);
#pragma unroll
            for (int ks = 0; ks < 4; ++ks) {
                short8 pf = *(const short8*)&myP[l15 * 136 + ks * 32 + kl];
#pragma unroll
                for (int ni = 0; ni < 2; ++ni) {
                    short8 vf = *(const short8*)&Vt[(ni * 16 + l15) * 264 + half * 128 + ks * 32 + kl];
                    oacc[ni] = __builtin_amdgcn_mfma_f32_16x16x32_bf16(pf, vf, oacc[ni], 0, 0, 0);
                }
            }
        }

#pragma unroll
        for (int ni = 0; ni < 2; ++ni) {
            float gbv = ni ? gbc1 : gbc0;
#pragma unroll
            for (int r = 0; r < 4; r++) {
                float gate = 1.f / (1.f + __expf(-(acc2[mt][ni + 2][r] + gbv)));
                size_t idx = (((size_t)b << 8) + q0 + r) * 256 + h * 32 + ni * 16 + l15;
                WAo[idx] = f2bf(oacc[ni][r] * gate);
            }
        }
    }
}

__global__ __launch_bounds__(256) void gemm_out_k(
    const u16* __restrict__ X, const float* __restrict__ Wo,
    float* __restrict__ dst, const float* __restrict__ cbias)
{
    __shared__ u16 As[128 * 40];
    __shared__ u16 Bs[128 * 40];
    int tid = threadIdx.x;
    int lane = tid & 63, w = tid >> 6;
    int wm = w >> 1, wn = w & 1;
    int row0 = blockIdx.x * 128;
    int n0 = blockIdx.y * 128;
    int lr = tid >> 1;
    int lc = (tid & 1) << 4;

    const f32x4 fz = {0.f, 0.f, 0.f, 0.f};
    f32x4 acc[4][4];
#pragma unroll
    for (int i = 0; i < 4; i++)
#pragma unroll
        for (int j = 0; j < 4; j++) acc[i][j] = fz;

    int kl = (lane >> 4) << 3;
    int l15 = lane & 15;
    int rm = wm * 64 + l15;
    int rn = wn * 64 + l15;

    for (int kb = 0; kb < 8; ++kb) {
        int k0 = kb << 5;
        const u16* pa = X + ((size_t)(row0 + lr) << 8) + k0 + lc;
        u32x4 a0 = *(const u32x4*)pa;
        u32x4 a1 = *(const u32x4*)(pa + 8);
        int bk = tid >> 3, bn = (tid & 7) << 4;
        const float* pb = Wo + (size_t)(k0 + bk) * 256 + n0 + bn;
        u16 bu[16];
#pragma unroll
        for (int j = 0; j < 16; j += 4) {
            f32x4 x = *(const f32x4*)(pb + j);
            bu[j] = f2bf(x[0]); bu[j + 1] = f2bf(x[1]);
            bu[j + 2] = f2bf(x[2]); bu[j + 3] = f2bf(x[3]);
        }
        if (kb) __syncthreads();
        *(u32x4*)&As[lr * 40 + lc] = a0;
        *(u32x4*)&As[lr * 40 + lc + 8] = a1;
#pragma unroll
        for (int j = 0; j < 16; j++) Bs[(bn + j) * 40 + bk] = bu[j];
        __syncthreads();
        short8 af[4], bf[4];
#pragma unroll
        for (int i = 0; i < 4; i++) af[i] = *(const short8*)&As[(rm + i * 16) * 40 + kl];
#pragma unroll
        for (int i = 0; i < 4; i++) bf[i] = *(const short8*)&Bs[(rn + i * 16) * 40 + kl];
#pragma unroll
        for (int mi = 0; mi < 4; mi++)
#pragma unroll
            for (int ni = 0; ni < 4; ni++)
                acc[mi][ni] = __builtin_amdgcn_mfma_f32_16x16x32_bf16(af[mi], bf[ni], acc[mi][ni], 0, 0, 0);
    }

#pragma unroll
    for (int mi = 0; mi < 4; mi++)
#pragma unroll
        for (int ni = 0; ni < 4; ni++)
#pragma unroll
            for (int r = 0; r < 4; r++) {
                int row = row0 + wm * 64 + mi * 16 + ((lane >> 4) << 2) + r;
                int col = n0 + wn * 64 + ni * 16 + l15;
                dst[((size_t)row << 8) + col] = acc[mi][ni][r] + cbias[col];
            }
}

// ---------------------------------------------------------------------------
extern "C" void kernel_launch(void* const* d_in, const int* in_sizes, int n_in,
                              void* d_out, int out_size, void* d_ws, size_t ws_size,
                              hipStream_t stream)
{
    const float* q_data   = (const float*)d_in[0];
    const float* m_data   = (const float*)d_in[1];
    const float* bias     = (const float*)d_in[2];
    const float* nb       = (const float*)d_in[3];
    const float* query_w  = (const float*)d_in[4];
    const float* key_w    = (const float*)d_in[5];
    const float* value_w  = (const float*)d_in[6];
    const float* gating_w = (const float*)d_in[7];
    const float* gating_b = (const float*)d_in[8];
    const float* output_w = (const float*)d_in[9];
    const float* output_b = (const float*)d_in[10];

    const size_t NEED_A = 4ull * 33554432 + 524288 + 131072 + 1048576; // 135,921,664

    if (ws_size >= NEED_A) {
        // PATH A — fused projection+attention (no K/V/Q/G HBM round-trip)
        u16* ws   = (u16*)d_ws;
        u16* WA   = ws;                  // 16,777,216 u16 ([65536][256])
        u16* wt   = WA + 16777216;       // 262,144
        u16* WoT  = wt + 262144;         // 65,536
        u16* nbT  = WoT + 65536;         // 524,288  ([h][k][q] * log2e)

        prep_a<<<1408, 256, 0, stream>>>(nb, query_w, key_w, value_w, gating_w,
                                         output_w, wt, WoT, nbT);
        fusedA<<<2048, 256, 0, stream>>>(q_data, m_data, bias, nbT, wt, gating_b, WA);
        gemmout_a<<<dim3(512, 2), 256, 0, stream>>>(WA, WoT, (float*)d_out, output_b);
    } else {
        // PATH B — round-4 proven pipeline
        u16* WAb = (u16*)d_ws;
        u16* wt  = (u16*)d_out;
        transpose_k<<<1024, 256, 0, stream>>>(query_w, key_w, value_w, gating_w, wt);
        fused_attn_k<<<2048, 256, 0, stream>>>(q_data, m_data, bias, nb, wt, gating_b, WAb);
        gemm_out_k<<<dim3(512, 2), 256, 0, stream>>>(WAb, output_w, (float*)d_out, output_b);
    }
}

// Round 10
// 380.231 us; speedup vs baseline: 1.1875x; 1.1875x over previous
//
#include <hip/hip_runtime.h>

typedef unsigned short u16;
typedef __attribute__((ext_vector_type(8))) short short8;
typedef __attribute__((ext_vector_type(4))) float f32x4;
typedef __attribute__((ext_vector_type(4))) unsigned int u32x4;
typedef __attribute__((ext_vector_type(4))) unsigned short u16x4;

#define LOG2E 1.4426950408889634f

__device__ __forceinline__ float bf2f(u16 u) {
    union { float f; unsigned int i; } c; c.i = ((unsigned int)u) << 16; return c.f;
}
__device__ __forceinline__ u16 f2bf(float f) {
    unsigned int x = __float_as_uint(f);
    x += 0x7fff + ((x >> 16) & 1);   // RNE
    return (u16)(x >> 16);
}
// packed f32 pair -> 2x bf16 in one VALU op (RNE, gfx950)
__device__ __forceinline__ unsigned int cvtpk(float lo, float hi) {
    unsigned int d;
    asm("v_cvt_pk_bf16_f32 %0, %1, %2" : "=v"(d) : "v"(lo), "v"(hi));
    return d;
}

union Cvt32 { u32x4 v[4]; u16 u[32]; };

// load 32 consecutive fp32 and convert to 32 bf16 (cvtpk: 16 VALU ops)
__device__ __forceinline__ void ld32f_bf(const float* __restrict__ p, Cvt32& t) {
    union { unsigned int i[8]; u32x4 v[2]; } a;
#pragma unroll
    for (int j = 0; j < 4; j++) {
        f32x4 x = *(const f32x4*)(p + j * 4);
        a.i[j * 2]     = cvtpk(x[0], x[1]);
        a.i[j * 2 + 1] = cvtpk(x[2], x[3]);
    }
    t.v[0] = a.v[0]; t.v[1] = a.v[1];
#pragma unroll
    for (int j = 0; j < 4; j++) {
        f32x4 x = *(const f32x4*)(p + 16 + j * 4);
        a.i[j * 2]     = cvtpk(x[0], x[1]);
        a.i[j * 2 + 1] = cvtpk(x[2], x[3]);
    }
    t.v[2] = a.v[0]; t.v[3] = a.v[1];
}

// ===========================================================================
// ============================ PATH A (large ws) ============================
// ===========================================================================

// Prep: proj weights -> wt (per-head [half][h][n][k] layout, n<32 = K/Q,
// n>=32 = V/G), output_w -> WoT[o][hc], nb -> nbT[h][k][q]*LOG2E bf16.
__global__ __launch_bounds__(256) void prep_a(
    const float* __restrict__ nb,
    const float* __restrict__ qw, const float* __restrict__ kw,
    const float* __restrict__ vw, const float* __restrict__ gw,
    const float* __restrict__ ow,
    u16* __restrict__ wt, u16* __restrict__ WoT, u16* __restrict__ nbT)
{
    __shared__ float tile[64][65];
    int blk = blockIdx.x, tid = threadIdx.x;
    if (blk < 1024) {
        int i = blk * 256 + tid;             // 0..262143
        int half = i >> 17;
        int rem = i & 131071;
        int h = rem >> 14, e = rem & 16383;
        int n = e >> 8, k = e & 255;
        int src_idx = k * 256 + h * 32 + (n & 31);
        float v;
        if (half == 0) v = (n < 32) ? kw[src_idx] : vw[src_idx];
        else           v = (n < 32) ? qw[src_idx] : gw[src_idx];
        wt[i] = f2bf(v);
    } else if (blk < 1280) {
        int e = (blk - 1024) * 256 + tid;    // 0..65535
        int o = e & 255, hc = e >> 8;
        WoT[o * 256 + hc] = f2bf(ow[hc * 256 + o]);
    } else {
        int idx = blk - 1280;                // 0..127
        int q0 = (idx & 3) * 64, k0 = ((idx >> 2) & 3) * 64, h = idx >> 4;
        int rr = tid >> 4;                   // 0..15
        int cc = (tid & 15) << 2;            // 0,4,..,60
        const float* src = nb + ((size_t)(h * 256 + q0)) * 256 + k0;
#pragma unroll
        for (int p = 0; p < 4; p++) {
            int q = rr + p * 16;
            f32x4 x = *(const f32x4*)(src + (size_t)q * 256 + cc);
            tile[q][cc] = x[0]; tile[q][cc + 1] = x[1];
            tile[q][cc + 2] = x[2]; tile[q][cc + 3] = x[3];
        }
        __syncthreads();
        u16* dst = nbT + ((size_t)(h * 256 + k0)) * 256 + q0;
#pragma unroll
        for (int p = 0; p < 4; p++) {
            int k = rr + p * 16;
            u16x4 o;
#pragma unroll
            for (int u = 0; u < 4; u++) o[u] = f2bf(tile[cc + u][k] * LOG2E);
            *(u16x4*)(dst + (size_t)k * 256 + cc) = o;
        }
    }
}

// Fused projection + attention per (b,h). Round-10: same as round 9 but
// WITHOUT the `,3` launch-bounds hint — that hint made the allocator
// squeeze to 84 VGPRs and spill acc2 (64 regs, live across all phases)
// to scratch: WRITE_SIZE 33->186 MB, FETCH +74 MB (spill+reload measured
// exactly = 64 f32/thread). LDS 51,712 B already allows 3 blocks/CU at
// the compiler's natural 128-VGPR allocation (needs <=168).
__global__ __launch_bounds__(256) void fusedA(
    const float* __restrict__ q_data, const float* __restrict__ m_data,
    const float* __restrict__ bias2, const u16* __restrict__ nbT,
    const u16* __restrict__ wt, const float* __restrict__ gb,
    u16* __restrict__ WA)
{
    __shared__ u16 smem[25856];          // 51,712 B
    u16* Vt  = smem;                     // [32][264]   8,448 u16
    u16* Xs  = smem + 8448;              // [256][40]  10,240 u16 -> becomes Ksh
    u16* Ksh = Xs;                       //   (aliased: K written in-place)
    u16* Wsh = smem + 18688;             // [64][40]    2,560 u16 (proj only)

    int bid = blockIdx.x;
    int b = bid >> 3, h = bid & 7;
    int tid = threadIdx.x, lane = tid & 63, w = tid >> 6;
    int l15 = lane & 15;
    int kl = (lane >> 4) << 3;
    int rq = (lane >> 4) << 2;
    const f32x4 fz = {0.f, 0.f, 0.f, 0.f};

    float bload[16];
#pragma unroll
    for (int t = 0; t < 16; t++)
        bload[t] = bias2[(b << 8) + t * 16 + l15] * LOG2E;
    float gbc0 = gb[h * 32 + l15];
    float gbc1 = gb[h * 32 + 16 + l15];

    int srow = tid >> 1;                 // 0..127 (staging row within pass)
    int sc16 = (tid & 1) << 4;           // f32 col 0 / 16
    int nrow = tid >> 1, nc = (tid & 1) << 4;

    // ---------- phase 1: Q,G projection (X = q_data[b]) -> acc2 regs --------
    const float* Xg2 = q_data + ((size_t)b << 16);
    const u16* Wg2 = wt + 131072 + (h << 14);
    f32x4 acc2[4][4];
#pragma unroll
    for (int i = 0; i < 4; i++)
#pragma unroll
        for (int j = 0; j < 4; j++) acc2[i][j] = fz;

    for (int kb = 0; kb < 8; ++kb) {
        // coalesced A-stage: 2 passes x (2 thr/row x 128 rows), 64B/thread
        u32x4 c0[2], c1[2];
#pragma unroll
        for (int p = 0; p < 2; ++p) {
            const float* ps = Xg2 + (size_t)(p * 128 + srow) * 256 + kb * 32 + sc16;
            f32x4 x0 = *(const f32x4*)ps;
            f32x4 x1 = *(const f32x4*)(ps + 4);
            f32x4 x2 = *(const f32x4*)(ps + 8);
            f32x4 x3 = *(const f32x4*)(ps + 12);
            union { unsigned int i4[4]; u32x4 v; } a, c;
            a.i4[0] = cvtpk(x0[0], x0[1]); a.i4[1] = cvtpk(x0[2], x0[3]);
            a.i4[2] = cvtpk(x1[0], x1[1]); a.i4[3] = cvtpk(x1[2], x1[3]);
            c.i4[0] = cvtpk(x2[0], x2[1]); c.i4[1] = cvtpk(x2[2], x2[3]);
            c.i4[2] = cvtpk(x3[0], x3[1]); c.i4[3] = cvtpk(x3[2], x3[3]);
            c0[p] = a.v; c1[p] = c.v;
        }
        u32x4 b0, b1;
        if (tid < 128) {
            const u16* q = Wg2 + nrow * 256 + kb * 32 + nc;
            b0 = *(const u32x4*)q; b1 = *(const u32x4*)(q + 8);
        }
        if (kb) __syncthreads();
#pragma unroll
        for (int p = 0; p < 2; ++p) {
            int row = p * 128 + srow;
            *(u32x4*)&Xs[row * 40 + sc16]     = c0[p];
            *(u32x4*)&Xs[row * 40 + sc16 + 8] = c1[p];
        }
        if (tid < 128) {
            *(u32x4*)&Wsh[nrow * 40 + nc] = b0;
            *(u32x4*)&Wsh[nrow * 40 + nc + 8] = b1;
        }
        __syncthreads();
        short8 af[4], bf[4];
#pragma unroll
        for (int i = 0; i < 4; i++) af[i] = *(const short8*)&Xs[(64 * w + i * 16 + l15) * 40 + kl];
#pragma unroll
        for (int i = 0; i < 4; i++) bf[i] = *(const short8*)&Wsh[(i * 16 + l15) * 40 + kl];
#pragma unroll
        for (int mi = 0; mi < 4; mi++)
#pragma unroll
            for (int ni = 0; ni < 4; ni++)
                acc2[mi][ni] = __builtin_amdgcn_mfma_f32_16x16x32_bf16(af[mi], bf[ni], acc2[mi][ni], 0, 0, 0);
    }

    // ---------- phase 2: K,V projection (X = m_data[b]) -> Ksh(=Xs), Vt -----
    const float* Xg = m_data + ((size_t)b << 16);
    const u16* Wg = wt + (h << 14);
    f32x4 acc[4][4];
#pragma unroll
    for (int i = 0; i < 4; i++)
#pragma unroll
        for (int j = 0; j < 4; j++) acc[i][j] = fz;

    for (int kb = 0; kb < 8; ++kb) {
        u32x4 c0[2], c1[2];
#pragma unroll
        for (int p = 0; p < 2; ++p) {
            const float* ps = Xg + (size_t)(p * 128 + srow) * 256 + kb * 32 + sc16;
            f32x4 x0 = *(const f32x4*)ps;
            f32x4 x1 = *(const f32x4*)(ps + 4);
            f32x4 x2 = *(const f32x4*)(ps + 8);
            f32x4 x3 = *(const f32x4*)(ps + 12);
            union { unsigned int i4[4]; u32x4 v; } a, c;
            a.i4[0] = cvtpk(x0[0], x0[1]); a.i4[1] = cvtpk(x0[2], x0[3]);
            a.i4[2] = cvtpk(x1[0], x1[1]); a.i4[3] = cvtpk(x1[2], x1[3]);
            c.i4[0] = cvtpk(x2[0], x2[1]); c.i4[1] = cvtpk(x2[2], x2[3]);
            c.i4[2] = cvtpk(x3[0], x3[1]); c.i4[3] = cvtpk(x3[2], x3[3]);
            c0[p] = a.v; c1[p] = c.v;
        }
        u32x4 b0, b1;
        if (tid < 128) {
            const u16* q = Wg + nrow * 256 + kb * 32 + nc;
            b0 = *(const u32x4*)q; b1 = *(const u32x4*)(q + 8);
        }
        __syncthreads();   // unconditional: protects phase-1 reads at kb=0
#pragma unroll
        for (int p = 0; p < 2; ++p) {
            int row = p * 128 + srow;
            *(u32x4*)&Xs[row * 40 + sc16]     = c0[p];
            *(u32x4*)&Xs[row * 40 + sc16 + 8] = c1[p];
        }
        if (tid < 128) {
            *(u32x4*)&Wsh[nrow * 40 + nc] = b0;
            *(u32x4*)&Wsh[nrow * 40 + nc + 8] = b1;
        }
        __syncthreads();
        short8 af[4], bf[4];
#pragma unroll
        for (int i = 0; i < 4; i++) af[i] = *(const short8*)&Xs[(64 * w + i * 16 + l15) * 40 + kl];
#pragma unroll
        for (int i = 0; i < 4; i++) bf[i] = *(const short8*)&Wsh[(i * 16 + l15) * 40 + kl];
#pragma unroll
        for (int mi = 0; mi < 4; mi++)
#pragma unroll
            for (int ni = 0; ni < 4; ni++)
                acc[mi][ni] = __builtin_amdgcn_mfma_f32_16x16x32_bf16(af[mi], bf[ni], acc[mi][ni], 0, 0, 0);
    }
    // epilogue: K into Ksh (in-place over this wave's own Xs band), V -> Vt
#pragma unroll
    for (int mi = 0; mi < 4; mi++)
#pragma unroll
        for (int ni = 0; ni < 4; ni++)
#pragma unroll
            for (int r = 0; r < 4; r++) {
                int s = 64 * w + mi * 16 + rq + r;
                int col = ni * 16 + l15;
                u16 v = f2bf(acc[mi][ni][r]);
                if (ni < 2) Ksh[s * 40 + col] = v;
                else        Vt[(col - 32) * 264 + s] = v;
            }
    __syncthreads();

    // ---------- phase 3: attention (fully unrolled mt — static acc2 idx) ----
    u16* myQ = smem + 18688 + w * 1792;  // per-wave: [16][40] (overlays Wsh+)
    u16* myP = myQ + 640;                // per-wave: [16][72]
    const u16* nbh = nbT + ((size_t)h << 16);
    const float qs = 0.17677669529663687f * LOG2E;
    int orow = lane >> 2, ocol = (lane & 3) << 3;

#pragma unroll
    for (int mt = 0; mt < 4; ++mt) {
        int q0 = 64 * w + mt * 16 + rq;
#pragma unroll
        for (int ni = 0; ni < 2; ++ni)
#pragma unroll
            for (int r = 0; r < 4; r++)
                myQ[(rq + r) * 40 + ni * 16 + l15] = f2bf(acc2[mt][ni][r] * qs);
        short8 qf = *(const short8*)&myQ[l15 * 40 + kl];

        const u16* nbp = nbh + q0;
        float srow_[4] = {0.f, 0.f, 0.f, 0.f};
        f32x4 oacc[2] = {fz, fz};
#pragma unroll
        for (int qt = 0; qt < 4; ++qt) {
            f32x4 sc[4];
#pragma unroll
            for (int t = 0; t < 4; t++) {
                int tt = qt * 4 + t;
                short8 kfr = *(const short8*)&Ksh[(tt * 16 + l15) * 40 + kl];
                f32x4 cb = {bload[tt], bload[tt], bload[tt], bload[tt]};
                sc[t] = __builtin_amdgcn_mfma_f32_16x16x32_bf16(qf, kfr, cb, 0, 0, 0);
            }
#pragma unroll
            for (int t = 0; t < 4; t++) {
                int tt = qt * 4 + t;
                u16x4 nbv = *(const u16x4*)(nbp + ((tt * 16 + l15) << 8));
#pragma unroll
                for (int r = 0; r < 4; r++) {
                    // no-max softmax in exp2 domain (|logit*log2e| << 127)
                    float p = __builtin_amdgcn_exp2f(sc[t][r] + bf2f(nbv[r]));
                    srow_[r] += p;
                    myP[(rq + r) * 72 + t * 16 + l15] = f2bf(p);
                }
            }
#pragma unroll
            for (int ks = 0; ks < 2; ++ks) {
                short8 pf = *(const short8*)&myP[l15 * 72 + ks * 32 + kl];
#pragma unroll
                for (int ni = 0; ni < 2; ++ni) {
                    short8 vf = *(const short8*)&Vt[(ni * 16 + l15) * 264 + qt * 64 + ks * 32 + kl];
                    oacc[ni] = __builtin_amdgcn_mfma_f32_16x16x32_bf16(pf, vf, oacc[ni], 0, 0, 0);
                }
            }
        }
#pragma unroll
        for (int r = 0; r < 4; r++) {
            float s = srow_[r];
            s += __shfl_xor(s, 1);
            s += __shfl_xor(s, 2);
            s += __shfl_xor(s, 4);
            s += __shfl_xor(s, 8);
            srow_[r] = __builtin_amdgcn_rcpf(s);
        }

        // gate from live acc2 (static mt), normalize, stage
#pragma unroll
        for (int ni = 0; ni < 2; ++ni) {
            float gbv = ni ? gbc1 : gbc0;
#pragma unroll
            for (int r = 0; r < 4; r++) {
                float gate = __builtin_amdgcn_rcpf(
                    1.f + __builtin_amdgcn_exp2f(-(acc2[mt][ni + 2][r] + gbv) * LOG2E));
                myP[(rq + r) * 40 + ni * 16 + l15] = f2bf(oacc[ni][r] * srow_[r] * gate);
            }
        }
        // coalesced store: WA[(b*256+q)][h*32+c], 16B/lane
        u32x4 ov = *(const u32x4*)&myP[orow * 40 + ocol];
        *(u32x4*)(WA + ((size_t)((b << 8) + 64 * w + mt * 16 + orow) << 8) + h * 32 + ocol) = ov;
    }
}

// Output GEMM: out[65536,256] = WA[65536,256](bf16) @ WoT^T + output_b.
__global__ __launch_bounds__(256) void gemmout_a(
    const u16* __restrict__ WA, const u16* __restrict__ WoT,
    float* __restrict__ dst, const float* __restrict__ ob)
{
    __shared__ u16 As[128 * 40];
    __shared__ u16 Bs[128 * 40];
    int tid = threadIdx.x;
    int lane = tid & 63, w = tid >> 6;
    int wm = w >> 1, wn = w & 1;
    int row0 = blockIdx.x * 128;
    int n0 = blockIdx.y * 128;
    int lr = tid >> 1;
    int lc = (tid & 1) << 4;

    const f32x4 fz = {0.f, 0.f, 0.f, 0.f};
    f32x4 acc[4][4];
#pragma unroll
    for (int i = 0; i < 4; i++)
#pragma unroll
        for (int j = 0; j < 4; j++) acc[i][j] = fz;

    int kl = (lane >> 4) << 3;
    int l15 = lane & 15;
    int rm = wm * 64 + l15;
    int rn = wn * 64 + l15;

    for (int kb = 0; kb < 8; ++kb) {
        int k0 = kb << 5;
        const u16* pa = WA + ((size_t)(row0 + lr) << 8) + k0 + lc;
        u32x4 a0 = *(const u32x4*)pa;
        u32x4 a1 = *(const u32x4*)(pa + 8);
        const u16* pb = WoT + ((size_t)(n0 + lr) << 8) + k0 + lc;
        u32x4 b0 = *(const u32x4*)pb;
        u32x4 b1 = *(const u32x4*)(pb + 8);
        if (kb) __syncthreads();
        *(u32x4*)&As[lr * 40 + lc] = a0;
        *(u32x4*)&As[lr * 40 + lc + 8] = a1;
        *(u32x4*)&Bs[lr * 40 + lc] = b0;
        *(u32x4*)&Bs[lr * 40 + lc + 8] = b1;
        __syncthreads();
        short8 af[4], bf[4];
#pragma unroll
        for (int i = 0; i < 4; i++) af[i] = *(const short8*)&As[(rm + i * 16) * 40 + kl];
#pragma unroll
        for (int i = 0; i < 4; i++) bf[i] = *(const short8*)&Bs[(rn + i * 16) * 40 + kl];
#pragma unroll
        for (int mi = 0; mi < 4; mi++)
#pragma unroll
            for (int ni = 0; ni < 4; ni++)
                acc[mi][ni] = __builtin_amdgcn_mfma_f32_16x16x32_bf16(af[mi], bf[ni], acc[mi][ni], 0, 0, 0);
    }

#pragma unroll
    for (int mi = 0; mi < 4; mi++)
#pragma unroll
        for (int ni = 0; ni < 4; ni++)
#pragma unroll
            for (int r = 0; r < 4; r++) {
                int row = row0 + wm * 64 + mi * 16 + ((lane >> 4) << 2) + r;
                int col = n0 + wn * 64 + ni * 16 + l15;
                dst[((size_t)row << 8) + col] = acc[mi][ni][r] + ob[col];
            }
}

// ===========================================================================
// ===================== PATH B (small ws) — round-4 code ====================
// ===========================================================================

__global__ __launch_bounds__(256) void transpose_k(
    const float* __restrict__ query_w, const float* __restrict__ key_w,
    const float* __restrict__ value_w, const float* __restrict__ gating_w,
    u16* __restrict__ wt)
{
    int i = blockIdx.x * 256 + threadIdx.x;
    int half = i >> 17;
    int rem = i & 131071;
    int h = rem >> 14, e = rem & 16383;
    int n = e >> 8, k = e & 255;
    int src_idx = k * 256 + h * 32 + (n & 31);
    float v;
    if (half == 0) v = (n < 32) ? key_w[src_idx]   : value_w[src_idx];
    else           v = (n < 32) ? query_w[src_idx] : gating_w[src_idx];
    wt[i] = f2bf(v);
}

__global__ __launch_bounds__(256) void fused_attn_k(
    const float* __restrict__ q_data, const float* __restrict__ m_data,
    const float* __restrict__ bias2, const float* __restrict__ nb,
    const u16* __restrict__ wt, const float* __restrict__ gb,
    u16* __restrict__ WAo)
{
    __shared__ u16 smem[31488];
    u16* Ksh = smem;
    u16* Vt  = smem + 10240;
    u16* Xs  = smem + 18688;
    u16* Wsh = smem + 28928;

    int bid = blockIdx.x;
    int b = bid >> 3, h = bid & 7;
    int tid = threadIdx.x, lane = tid & 63, w = tid >> 6;
    int l15 = lane & 15;
    int kl = (lane >> 4) << 3;
    int rq = (lane >> 4) << 2;
    const f32x4 fz = {0.f, 0.f, 0.f, 0.f};

    float bload[16];
#pragma unroll
    for (int t = 0; t < 16; t++) bload[t] = bias2[(b << 8) + t * 16 + l15];
    float gbc0 = gb[h * 32 + l15];
    float gbc1 = gb[h * 32 + 16 + l15];

    const float* Xg = m_data + ((size_t)b << 16);
    const u16* Wg = wt + (h << 14);
    f32x4 acc[4][4];
#pragma unroll
    for (int i = 0; i < 4; i++)
#pragma unroll
        for (int j = 0; j < 4; j++) acc[i][j] = fz;

    for (int kb = 0; kb < 8; ++kb) {
        Cvt32 am;
        ld32f_bf(Xg + (size_t)tid * 256 + kb * 32, am);
        u32x4 b0, b1;
        int nrow = tid >> 1, nc = (tid & 1) << 4;
        if (tid < 128) {
            const u16* q = Wg + nrow * 256 + kb * 32 + nc;
            b0 = *(const u32x4*)q; b1 = *(const u32x4*)(q + 8);
        }
        if (kb) __syncthreads();
        *(u32x4*)&Xs[tid * 40]      = am.v[0];
        *(u32x4*)&Xs[tid * 40 + 8]  = am.v[1];
        *(u32x4*)&Xs[tid * 40 + 16] = am.v[2];
        *(u32x4*)&Xs[tid * 40 + 24] = am.v[3];
        if (tid < 128) {
            *(u32x4*)&Wsh[nrow * 40 + nc] = b0;
            *(u32x4*)&Wsh[nrow * 40 + nc + 8] = b1;
        }
        __syncthreads();
        short8 af[4], bf[4];
#pragma unroll
        for (int i = 0; i < 4; i++) af[i] = *(const short8*)&Xs[(64 * w + i * 16 + l15) * 40 + kl];
#pragma unroll
        for (int i = 0; i < 4; i++) bf[i] = *(const short8*)&Wsh[(i * 16 + l15) * 40 + kl];
#pragma unroll
        for (int mi = 0; mi < 4; mi++)
#pragma unroll
            for (int ni = 0; ni < 4; ni++)
                acc[mi][ni] = __builtin_amdgcn_mfma_f32_16x16x32_bf16(af[mi], bf[ni], acc[mi][ni], 0, 0, 0);
    }
#pragma unroll
    for (int mi = 0; mi < 4; mi++)
#pragma unroll
        for (int ni = 0; ni < 4; ni++)
#pragma unroll
            for (int r = 0; r < 4; r++) {
                int s = 64 * w + mi * 16 + rq + r;
                int col = ni * 16 + l15;
                u16 v = f2bf(acc[mi][ni][r]);
                if (ni < 2) Ksh[s * 40 + col] = v;
                else        Vt[(col - 32) * 264 + s] = v;
            }
    __syncthreads();

    const float* Xg2 = q_data + ((size_t)b << 16);
    const u16* Wg2 = wt + 131072 + (h << 14);
    f32x4 acc2[4][4];
#pragma unroll
    for (int i = 0; i < 4; i++)
#pragma unroll
        for (int j = 0; j < 4; j++) acc2[i][j] = fz;

    for (int kb = 0; kb < 8; ++kb) {
        Cvt32 am;
        ld32f_bf(Xg2 + (size_t)tid * 256 + kb * 32, am);
        u32x4 b0, b1;
        int nrow = tid >> 1, nc = (tid & 1) << 4;
        if (tid < 128) {
            const u16* q = Wg2 + nrow * 256 + kb * 32 + nc;
            b0 = *(const u32x4*)q; b1 = *(const u32x4*)(q + 8);
        }
        __syncthreads();
        *(u32x4*)&Xs[tid * 40]      = am.v[0];
        *(u32x4*)&Xs[tid * 40 + 8]  = am.v[1];
        *(u32x4*)&Xs[tid * 40 + 16] = am.v[2];
        *(u32x4*)&Xs[tid * 40 + 24] = am.v[3];
        if (tid < 128) {
            *(u32x4*)&Wsh[nrow * 40 + nc] = b0;
            *(u32x4*)&Wsh[nrow * 40 + nc + 8] = b1;
        }
        __syncthreads();
        short8 af[4], bf[4];
#pragma unroll
        for (int i = 0; i < 4; i++) af[i] = *(const short8*)&Xs[(64 * w + i * 16 + l15) * 40 + kl];
#pragma unroll
        for (int i = 0; i < 4; i++) bf[i] = *(const short8*)&Wsh[(i * 16 + l15) * 40 + kl];
#pragma unroll
        for (int mi = 0; mi < 4; mi++)
#pragma unroll
            for (int ni = 0; ni < 4; ni++)
                acc2[mi][ni] = __builtin_amdgcn_mfma_f32_16x16x32_bf16(af[mi], bf[ni], acc2[mi][ni], 0, 0, 0);
    }
    __syncthreads();

    u16* myQ = smem + 18688 + w * 2816;
    u16* myP = myQ + 640;
    const float* nbp = nb + ((size_t)h << 16);
    const float qscale = 0.17677669529663687f;

#pragma unroll
    for (int mt = 0; mt < 4; ++mt) {
#pragma unroll
        for (int ni = 0; ni < 2; ++ni)
#pragma unroll
            for (int r = 0; r < 4; r++)
                myQ[(rq + r) * 40 + ni * 16 + l15] = f2bf(acc2[mt][ni][r] * qscale);

        short8 qf = *(const short8*)&myQ[l15 * 40 + kl];
        f32x4 sc[16];
#pragma unroll
        for (int t = 0; t < 16; t++) {
            short8 kfr = *(const short8*)&Ksh[(t * 16 + l15) * 40 + kl];
            sc[t] = __builtin_amdgcn_mfma_f32_16x16x32_bf16(qf, kfr, fz, 0, 0, 0);
        }

        int q0 = 64 * w + mt * 16 + rq;
        float mrow[4] = {-3e30f, -3e30f, -3e30f, -3e30f};
#pragma unroll
        for (int t = 0; t < 16; t++) {
            int kidx = t * 16 + l15;
#pragma unroll
            for (int r = 0; r < 4; r++) {
                float v = sc[t][r] + bload[t] + nbp[(size_t)(q0 + r) * 256 + kidx];
                sc[t][r] = v;
                mrow[r] = fmaxf(mrow[r], v);
            }
        }
#pragma unroll
        for (int r = 0; r < 4; r++) {
            float m = mrow[r];
            m = fmaxf(m, __shfl_xor(m, 1));
            m = fmaxf(m, __shfl_xor(m, 2));
            m = fmaxf(m, __shfl_xor(m, 4));
            m = fmaxf(m, __shfl_xor(m, 8));
            mrow[r] = m;
        }
        float srow[4] = {0.f, 0.f, 0.f, 0.f};
#pragma unroll
        for (int t = 0; t < 16; t++)
#pragma unroll
            for (int r = 0; r < 4; r++) {
                float p = __expf(sc[t][r] - mrow[r]);
                sc[t][r] = p;
                srow[r] += p;
            }
#pragma unroll
        for (int r = 0; r < 4; r++) {
            float s = srow[r];
            s += __shfl_xor(s, 1);
            s += __shfl_xor(s, 2);
            s += __shfl_xor(s, 4);
            s += __shfl_xor(s, 8);
            srow[r] = 1.f / s;
        }

        f32x4 oacc[2] = {fz, fz};
#pragma unroll
        for (int half = 0; half < 2; ++half) {
#pragma unroll
            for (int t = 0; t < 8; t++)
#pragma unroll
                for (int r = 0; r < 4; r++)
                    myP[(rq + r) * 136 + t * 16 + l15] =
                        f2bf(sc[half * 8 + t][r] * srow[r]);
#pragma unroll
            for (int ks = 0; ks < 4; ++ks) {
                short8 pf = *(const short8*)&myP[l15 * 136 + ks * 32 + kl];
#pragma unroll
                for (int ni = 0; ni < 2; ++ni) {
                    short8 vf = *(const short8*)&Vt[(ni * 16 + l15) * 264 + half * 128 + ks * 32 + kl];
                    oacc[ni] = __builtin_amdgcn_mfma_f32_16x16x32_bf16(pf, vf, oacc[ni], 0, 0, 0);
                }
            }
        }

#pragma unroll
        for (int ni = 0; ni < 2; ++ni) {
            float gbv = ni ? gbc1 : gbc0;
#pragma unroll
            for (int r = 0; r < 4; r++) {
                float gate = 1.f / (1.f + __expf(-(acc2[mt][ni + 2][r] + gbv)));
                size_t idx = (((size_t)b << 8) + q0 + r) * 256 + h * 32 + ni * 16 + l15;
                WAo[idx] = f2bf(oacc[ni][r] * gate);
            }
        }
    }
}

__global__ __launch_bounds__(256) void gemm_out_k(
    const u16* __restrict__ X, const float* __restrict__ Wo,
    float* __restrict__ dst, const float* __restrict__ cbias)
{
    __shared__ u16 As[128 * 40];
    __shared__ u16 Bs[128 * 40];
    int tid = threadIdx.x;
    int lane = tid & 63, w = tid >> 6;
    int wm = w >> 1, wn = w & 1;
    int row0 = blockIdx.x * 128;
    int n0 = blockIdx.y * 128;
    int lr = tid >> 1;
    int lc = (tid & 1) << 4;

    const f32x4 fz = {0.f, 0.f, 0.f, 0.f};
    f32x4 acc[4][4];
#pragma unroll
    for (int i = 0; i < 4; i++)
#pragma unroll
        for (int j = 0; j < 4; j++) acc[i][j] = fz;

    int kl = (lane >> 4) << 3;
    int l15 = lane & 15;
    int rm = wm * 64 + l15;
    int rn = wn * 64 + l15;

    for (int kb = 0; kb < 8; ++kb) {
        int k0 = kb << 5;
        const u16* pa = X + ((size_t)(row0 + lr) << 8) + k0 + lc;
        u32x4 a0 = *(const u32x4*)pa;
        u32x4 a1 = *(const u32x4*)(pa + 8);
        int bk = tid >> 3, bn = (tid & 7) << 4;
        const float* pb = Wo + (size_t)(k0 + bk) * 256 + n0 + bn;
        u16 bu[16];
#pragma unroll
        for (int j = 0; j < 16; j += 4) {
            f32x4 x = *(const f32x4*)(pb + j);
            bu[j] = f2bf(x[0]); bu[j + 1] = f2bf(x[1]);
            bu[j + 2] = f2bf(x[2]); bu[j + 3] = f2bf(x[3]);
        }
        if (kb) __syncthreads();
        *(u32x4*)&As[lr * 40 + lc] = a0;
        *(u32x4*)&As[lr * 40 + lc + 8] = a1;
#pragma unroll
        for (int j = 0; j < 16; j++) Bs[(bn + j) * 40 + bk] = bu[j];
        __syncthreads();
        short8 af[4], bf[4];
#pragma unroll
        for (int i = 0; i < 4; i++) af[i] = *(const short8*)&As[(rm + i * 16) * 40 + kl];
#pragma unroll
        for (int i = 0; i < 4; i++) bf[i] = *(const short8*)&Bs[(rn + i * 16) * 40 + kl];
#pragma unroll
        for (int mi = 0; mi < 4; mi++)
#pragma unroll
            for (int ni = 0; ni < 4; ni++)
                acc[mi][ni] = __builtin_amdgcn_mfma_f32_16x16x32_bf16(af[mi], bf[ni], acc[mi][ni], 0, 0, 0);
    }

#pragma unroll
    for (int mi = 0; mi < 4; mi++)
#pragma unroll
        for (int ni = 0; ni < 4; ni++)
#pragma unroll
            for (int r = 0; r < 4; r++) {
                int row = row0 + wm * 64 + mi * 16 + ((lane >> 4) << 2) + r;
                int col = n0 + wn * 64 + ni * 16 + l15;
                dst[((size_t)row << 8) + col] = acc[mi][ni][r] + cbias[col];
            }
}

// ---------------------------------------------------------------------------
extern "C" void kernel_launch(void* const* d_in, const int* in_sizes, int n_in,
                              void* d_out, int out_size, void* d_ws, size_t ws_size,
                              hipStream_t stream)
{
    const float* q_data   = (const float*)d_in[0];
    const float* m_data   = (const float*)d_in[1];
    const float* bias     = (const float*)d_in[2];
    const float* nb       = (const float*)d_in[3];
    const float* query_w  = (const float*)d_in[4];
    const float* key_w    = (const float*)d_in[5];
    const float* value_w  = (const float*)d_in[6];
    const float* gating_w = (const float*)d_in[7];
    const float* gating_b = (const float*)d_in[8];
    const float* output_w = (const float*)d_in[9];
    const float* output_b = (const float*)d_in[10];

    const size_t NEED_A = 4ull * 33554432 + 524288 + 131072 + 1048576; // 135,921,664

    if (ws_size >= NEED_A) {
        // PATH A — fused projection+attention (no K/V/Q/G HBM round-trip)
        u16* ws   = (u16*)d_ws;
        u16* WA   = ws;                  // 16,777,216 u16 ([65536][256])
        u16* wt   = WA + 16777216;       // 262,144
        u16* WoT  = wt + 262144;         // 65,536
        u16* nbT  = WoT + 65536;         // 524,288  ([h][k][q] * log2e)

        prep_a<<<1408, 256, 0, stream>>>(nb, query_w, key_w, value_w, gating_w,
                                         output_w, wt, WoT, nbT);
        fusedA<<<2048, 256, 0, stream>>>(q_data, m_data, bias, nbT, wt, gating_b, WA);
        gemmout_a<<<dim3(512, 2), 256, 0, stream>>>(WA, WoT, (float*)d_out, output_b);
    } else {
        // PATH B — round-4 proven pipeline
        u16* WAb = (u16*)d_ws;
        u16* wt  = (u16*)d_out;
        transpose_k<<<1024, 256, 0, stream>>>(query_w, key_w, value_w, gating_w, wt);
        fused_attn_k<<<2048, 256, 0, stream>>>(q_data, m_data, bias, nb, wt, gating_b, WAb);
        gemm_out_k<<<dim3(512, 2), 256, 0, stream>>>(WAb, output_w, (float*)d_out, output_b);
    }
}

// Round 12
// 371.897 us; speedup vs baseline: 1.2141x; 1.0224x over previous
//
#include <hip/hip_runtime.h>

typedef unsigned short u16;
typedef __attribute__((ext_vector_type(8))) short short8;
typedef __attribute__((ext_vector_type(4))) float f32x4;
typedef __attribute__((ext_vector_type(4))) unsigned int u32x4;
typedef __attribute__((ext_vector_type(4))) unsigned short u16x4;

#define LOG2E 1.4426950408889634f

__device__ __forceinline__ float bf2f(u16 u) {
    union { float f; unsigned int i; } c; c.i = ((unsigned int)u) << 16; return c.f;
}
__device__ __forceinline__ u16 f2bf(float f) {
    unsigned int x = __float_as_uint(f);
    x += 0x7fff + ((x >> 16) & 1);   // RNE
    return (u16)(x >> 16);
}
// packed f32 pair -> 2x bf16 in one VALU op (RNE, gfx950)
__device__ __forceinline__ unsigned int cvtpk(float lo, float hi) {
    unsigned int d;
    asm("v_cvt_pk_bf16_f32 %0, %1, %2" : "=v"(d) : "v"(lo), "v"(hi));
    return d;
}

union Cvt32 { u32x4 v[4]; u16 u[32]; };

// load 32 consecutive fp32 and convert to 32 bf16 (cvtpk: 16 VALU ops)
__device__ __forceinline__ void ld32f_bf(const float* __restrict__ p, Cvt32& t) {
    union { unsigned int i[8]; u32x4 v[2]; } a;
#pragma unroll
    for (int j = 0; j < 4; j++) {
        f32x4 x = *(const f32x4*)(p + j * 4);
        a.i[j * 2]     = cvtpk(x[0], x[1]);
        a.i[j * 2 + 1] = cvtpk(x[2], x[3]);
    }
    t.v[0] = a.v[0]; t.v[1] = a.v[1];
#pragma unroll
    for (int j = 0; j < 4; j++) {
        f32x4 x = *(const f32x4*)(p + 16 + j * 4);
        a.i[j * 2]     = cvtpk(x[0], x[1]);
        a.i[j * 2 + 1] = cvtpk(x[2], x[3]);
    }
    t.v[2] = a.v[0]; t.v[3] = a.v[1];
}

// ===========================================================================
// ============================ PATH A (large ws) ============================
// ===========================================================================

// Prep: proj weights -> wt (per-head [half][h][n][k] layout, n<32 = K/Q,
// n>=32 = V/G), output_w -> WoT[o][hc], nb -> nbT[h][k][q]*LOG2E bf16.
__global__ __launch_bounds__(256) void prep_a(
    const float* __restrict__ nb,
    const float* __restrict__ qw, const float* __restrict__ kw,
    const float* __restrict__ vw, const float* __restrict__ gw,
    const float* __restrict__ ow,
    u16* __restrict__ wt, u16* __restrict__ WoT, u16* __restrict__ nbT)
{
    __shared__ float tile[64][65];
    int blk = blockIdx.x, tid = threadIdx.x;
    if (blk < 1024) {
        int i = blk * 256 + tid;             // 0..262143
        int half = i >> 17;
        int rem = i & 131071;
        int h = rem >> 14, e = rem & 16383;
        int n = e >> 8, k = e & 255;
        int src_idx = k * 256 + h * 32 + (n & 31);
        float v;
        if (half == 0) v = (n < 32) ? kw[src_idx] : vw[src_idx];
        else           v = (n < 32) ? qw[src_idx] : gw[src_idx];
        wt[i] = f2bf(v);
    } else if (blk < 1280) {
        int e = (blk - 1024) * 256 + tid;    // 0..65535
        int o = e & 255, hc = e >> 8;
        WoT[o * 256 + hc] = f2bf(ow[hc * 256 + o]);
    } else {
        int idx = blk - 1280;                // 0..127
        int q0 = (idx & 3) * 64, k0 = ((idx >> 2) & 3) * 64, h = idx >> 4;
        int rr = tid >> 4;                   // 0..15
        int cc = (tid & 15) << 2;            // 0,4,..,60
        const float* src = nb + ((size_t)(h * 256 + q0)) * 256 + k0;
#pragma unroll
        for (int p = 0; p < 4; p++) {
            int q = rr + p * 16;
            f32x4 x = *(const f32x4*)(src + (size_t)q * 256 + cc);
            tile[q][cc] = x[0]; tile[q][cc + 1] = x[1];
            tile[q][cc + 2] = x[2]; tile[q][cc + 3] = x[3];
        }
        __syncthreads();
        u16* dst = nbT + ((size_t)(h * 256 + k0)) * 256 + q0;
#pragma unroll
        for (int p = 0; p < 4; p++) {
            int k = rr + p * 16;
            u16x4 o;
#pragma unroll
            for (int u = 0; u < 4; u++) o[u] = f2bf(tile[cc + u][k] * LOG2E);
            *(u16x4*)(dst + (size_t)k * 256 + cc) = o;
        }
    }
}

// Fused projection + attention per (b,h). Round-12 == round-11 resubmit
// (bench infra failed; no on-device signal). XCD-aware grid swizzle:
// old mapping (b = bid>>3, h = bid&7) put the 8 same-b blocks — which all
// read the SAME 512 KB slice of m_data/q_data — on 8 DIFFERENT XCDs.
// Per-XCD L2s are private, so each XCD streamed the full 134 MB of m+q
// independently (FETCH = 528 MB for ~135 MB unique, r10). New mapping:
// xcd owns a contiguous 32-wide b chunk; the 8 h-blocks of one b run
// back-to-back on the SAME XCD -> 7/8 of m/q reads become L2 hits.
__global__ __launch_bounds__(256) void fusedA(
    const float* __restrict__ q_data, const float* __restrict__ m_data,
    const float* __restrict__ bias2, const u16* __restrict__ nbT,
    const u16* __restrict__ wt, const float* __restrict__ gb,
    u16* __restrict__ WA)
{
    __shared__ u16 smem[25856];          // 51,712 B
    u16* Vt  = smem;                     // [32][264]   8,448 u16
    u16* Xs  = smem + 8448;              // [256][40]  10,240 u16 -> becomes Ksh
    u16* Ksh = Xs;                       //   (aliased: K written in-place)
    u16* Wsh = smem + 18688;             // [64][40]    2,560 u16 (proj only)

    int bid = blockIdx.x;
    // XCD-aware swizzle (bijective over 2048): xcd = bid&7 gets b-chunk
    // [32*xcd, 32*xcd+32); same-b h-blocks are 8 consecutive j -> L2-hot.
    int xcd = bid & 7;
    int j = bid >> 3;
    int h = j & 7;
    int b = (xcd << 5) | (j >> 3);
    int tid = threadIdx.x, lane = tid & 63, w = tid >> 6;
    int l15 = lane & 15;
    int kl = (lane >> 4) << 3;
    int rq = (lane >> 4) << 2;
    const f32x4 fz = {0.f, 0.f, 0.f, 0.f};

    float bload[16];
#pragma unroll
    for (int t = 0; t < 16; t++)
        bload[t] = bias2[(b << 8) + t * 16 + l15] * LOG2E;
    float gbc0 = gb[h * 32 + l15];
    float gbc1 = gb[h * 32 + 16 + l15];

    int srow = tid >> 1;                 // 0..127 (staging row within pass)
    int sc16 = (tid & 1) << 4;           // f32 col 0 / 16
    int nrow = tid >> 1, nc = (tid & 1) << 4;

    // ---------- phase 1: Q,G projection (X = q_data[b]) -> acc2 regs --------
    const float* Xg2 = q_data + ((size_t)b << 16);
    const u16* Wg2 = wt + 131072 + (h << 14);
    f32x4 acc2[4][4];
#pragma unroll
    for (int i = 0; i < 4; i++)
#pragma unroll
        for (int j2 = 0; j2 < 4; j2++) acc2[i][j2] = fz;

    for (int kb = 0; kb < 8; ++kb) {
        // coalesced A-stage: 2 passes x (2 thr/row x 128 rows), 64B/thread
        u32x4 c0[2], c1[2];
#pragma unroll
        for (int p = 0; p < 2; ++p) {
            const float* ps = Xg2 + (size_t)(p * 128 + srow) * 256 + kb * 32 + sc16;
            f32x4 x0 = *(const f32x4*)ps;
            f32x4 x1 = *(const f32x4*)(ps + 4);
            f32x4 x2 = *(const f32x4*)(ps + 8);
            f32x4 x3 = *(const f32x4*)(ps + 12);
            union { unsigned int i4[4]; u32x4 v; } a, c;
            a.i4[0] = cvtpk(x0[0], x0[1]); a.i4[1] = cvtpk(x0[2], x0[3]);
            a.i4[2] = cvtpk(x1[0], x1[1]); a.i4[3] = cvtpk(x1[2], x1[3]);
            c.i4[0] = cvtpk(x2[0], x2[1]); c.i4[1] = cvtpk(x2[2], x2[3]);
            c.i4[2] = cvtpk(x3[0], x3[1]); c.i4[3] = cvtpk(x3[2], x3[3]);
            c0[p] = a.v; c1[p] = c.v;
        }
        u32x4 b0, b1;
        if (tid < 128) {
            const u16* q = Wg2 + nrow * 256 + kb * 32 + nc;
            b0 = *(const u32x4*)q; b1 = *(const u32x4*)(q + 8);
        }
        if (kb) __syncthreads();
#pragma unroll
        for (int p = 0; p < 2; ++p) {
            int row = p * 128 + srow;
            *(u32x4*)&Xs[row * 40 + sc16]     = c0[p];
            *(u32x4*)&Xs[row * 40 + sc16 + 8] = c1[p];
        }
        if (tid < 128) {
            *(u32x4*)&Wsh[nrow * 40 + nc] = b0;
            *(u32x4*)&Wsh[nrow * 40 + nc + 8] = b1;
        }
        __syncthreads();
        short8 af[4], bf[4];
#pragma unroll
        for (int i = 0; i < 4; i++) af[i] = *(const short8*)&Xs[(64 * w + i * 16 + l15) * 40 + kl];
#pragma unroll
        for (int i = 0; i < 4; i++) bf[i] = *(const short8*)&Wsh[(i * 16 + l15) * 40 + kl];
#pragma unroll
        for (int mi = 0; mi < 4; mi++)
#pragma unroll
            for (int ni = 0; ni < 4; ni++)
                acc2[mi][ni] = __builtin_amdgcn_mfma_f32_16x16x32_bf16(af[mi], bf[ni], acc2[mi][ni], 0, 0, 0);
    }

    // ---------- phase 2: K,V projection (X = m_data[b]) -> Ksh(=Xs), Vt -----
    const float* Xg = m_data + ((size_t)b << 16);
    const u16* Wg = wt + (h << 14);
    f32x4 acc[4][4];
#pragma unroll
    for (int i = 0; i < 4; i++)
#pragma unroll
        for (int j2 = 0; j2 < 4; j2++) acc[i][j2] = fz;

    for (int kb = 0; kb < 8; ++kb) {
        u32x4 c0[2], c1[2];
#pragma unroll
        for (int p = 0; p < 2; ++p) {
            const float* ps = Xg + (size_t)(p * 128 + srow) * 256 + kb * 32 + sc16;
            f32x4 x0 = *(const f32x4*)ps;
            f32x4 x1 = *(const f32x4*)(ps + 4);
            f32x4 x2 = *(const f32x4*)(ps + 8);
            f32x4 x3 = *(const f32x4*)(ps + 12);
            union { unsigned int i4[4]; u32x4 v; } a, c;
            a.i4[0] = cvtpk(x0[0], x0[1]); a.i4[1] = cvtpk(x0[2], x0[3]);
            a.i4[2] = cvtpk(x1[0], x1[1]); a.i4[3] = cvtpk(x1[2], x1[3]);
            c.i4[0] = cvtpk(x2[0], x2[1]); c.i4[1] = cvtpk(x2[2], x2[3]);
            c.i4[2] = cvtpk(x3[0], x3[1]); c.i4[3] = cvtpk(x3[2], x3[3]);
            c0[p] = a.v; c1[p] = c.v;
        }
        u32x4 b0, b1;
        if (tid < 128) {
            const u16* q = Wg + nrow * 256 + kb * 32 + nc;
            b0 = *(const u32x4*)q; b1 = *(const u32x4*)(q + 8);
        }
        __syncthreads();   // unconditional: protects phase-1 reads at kb=0
#pragma unroll
        for (int p = 0; p < 2; ++p) {
            int row = p * 128 + srow;
            *(u32x4*)&Xs[row * 40 + sc16]     = c0[p];
            *(u32x4*)&Xs[row * 40 + sc16 + 8] = c1[p];
        }
        if (tid < 128) {
            *(u32x4*)&Wsh[nrow * 40 + nc] = b0;
            *(u32x4*)&Wsh[nrow * 40 + nc + 8] = b1;
        }
        __syncthreads();
        short8 af[4], bf[4];
#pragma unroll
        for (int i = 0; i < 4; i++) af[i] = *(const short8*)&Xs[(64 * w + i * 16 + l15) * 40 + kl];
#pragma unroll
        for (int i = 0; i < 4; i++) bf[i] = *(const short8*)&Wsh[(i * 16 + l15) * 40 + kl];
#pragma unroll
        for (int mi = 0; mi < 4; mi++)
#pragma unroll
            for (int ni = 0; ni < 4; ni++)
                acc[mi][ni] = __builtin_amdgcn_mfma_f32_16x16x32_bf16(af[mi], bf[ni], acc[mi][ni], 0, 0, 0);
    }
    // epilogue: K into Ksh (in-place over this wave's own Xs band), V -> Vt
#pragma unroll
    for (int mi = 0; mi < 4; mi++)
#pragma unroll
        for (int ni = 0; ni < 4; ni++)
#pragma unroll
            for (int r = 0; r < 4; r++) {
                int s = 64 * w + mi * 16 + rq + r;
                int col = ni * 16 + l15;
                u16 v = f2bf(acc[mi][ni][r]);
                if (ni < 2) Ksh[s * 40 + col] = v;
                else        Vt[(col - 32) * 264 + s] = v;
            }
    __syncthreads();

    // ---------- phase 3: attention (fully unrolled mt — static acc2 idx) ----
    u16* myQ = smem + 18688 + w * 1792;  // per-wave: [16][40] (overlays Wsh+)
    u16* myP = myQ + 640;                // per-wave: [16][72]
    const u16* nbh = nbT + ((size_t)h << 16);
    const float qs = 0.17677669529663687f * LOG2E;
    int orow = lane >> 2, ocol = (lane & 3) << 3;

#pragma unroll
    for (int mt = 0; mt < 4; ++mt) {
        int q0 = 64 * w + mt * 16 + rq;
#pragma unroll
        for (int ni = 0; ni < 2; ++ni)
#pragma unroll
            for (int r = 0; r < 4; r++)
                myQ[(rq + r) * 40 + ni * 16 + l15] = f2bf(acc2[mt][ni][r] * qs);
        short8 qf = *(const short8*)&myQ[l15 * 40 + kl];

        const u16* nbp = nbh + q0;
        float srow_[4] = {0.f, 0.f, 0.f, 0.f};
        f32x4 oacc[2] = {fz, fz};
#pragma unroll
        for (int qt = 0; qt < 4; ++qt) {
            f32x4 sc[4];
#pragma unroll
            for (int t = 0; t < 4; t++) {
                int tt = qt * 4 + t;
                short8 kfr = *(const short8*)&Ksh[(tt * 16 + l15) * 40 + kl];
                f32x4 cb = {bload[tt], bload[tt], bload[tt], bload[tt]};
                sc[t] = __builtin_amdgcn_mfma_f32_16x16x32_bf16(qf, kfr, cb, 0, 0, 0);
            }
#pragma unroll
            for (int t = 0; t < 4; t++) {
                int tt = qt * 4 + t;
                u16x4 nbv = *(const u16x4*)(nbp + ((tt * 16 + l15) << 8));
#pragma unroll
                for (int r = 0; r < 4; r++) {
                    // no-max softmax in exp2 domain (|logit*log2e| << 127)
                    float p = __builtin_amdgcn_exp2f(sc[t][r] + bf2f(nbv[r]));
                    srow_[r] += p;
                    myP[(rq + r) * 72 + t * 16 + l15] = f2bf(p);
                }
            }
#pragma unroll
            for (int ks = 0; ks < 2; ++ks) {
                short8 pf = *(const short8*)&myP[l15 * 72 + ks * 32 + kl];
#pragma unroll
                for (int ni = 0; ni < 2; ++ni) {
                    short8 vf = *(const short8*)&Vt[(ni * 16 + l15) * 264 + qt * 64 + ks * 32 + kl];
                    oacc[ni] = __builtin_amdgcn_mfma_f32_16x16x32_bf16(pf, vf, oacc[ni], 0, 0, 0);
                }
            }
        }
#pragma unroll
        for (int r = 0; r < 4; r++) {
            float s = srow_[r];
            s += __shfl_xor(s, 1);
            s += __shfl_xor(s, 2);
            s += __shfl_xor(s, 4);
            s += __shfl_xor(s, 8);
            srow_[r] = __builtin_amdgcn_rcpf(s);
        }

        // gate from live acc2 (static mt), normalize, stage
#pragma unroll
        for (int ni = 0; ni < 2; ++ni) {
            float gbv = ni ? gbc1 : gbc0;
#pragma unroll
            for (int r = 0; r < 4; r++) {
                float gate = __builtin_amdgcn_rcpf(
                    1.f + __builtin_amdgcn_exp2f(-(acc2[mt][ni + 2][r] + gbv) * LOG2E));
                myP[(rq + r) * 40 + ni * 16 + l15] = f2bf(oacc[ni][r] * srow_[r] * gate);
            }
        }
        // coalesced store: WA[(b*256+q)][h*32+c], 16B/lane
        u32x4 ov = *(const u32x4*)&myP[orow * 40 + ocol];
        *(u32x4*)(WA + ((size_t)((b << 8) + 64 * w + mt * 16 + orow) << 8) + h * 32 + ocol) = ov;
    }
}

// Output GEMM: out[65536,256] = WA[65536,256](bf16) @ WoT^T + output_b.
__global__ __launch_bounds__(256) void gemmout_a(
    const u16* __restrict__ WA, const u16* __restrict__ WoT,
    float* __restrict__ dst, const float* __restrict__ ob)
{
    __shared__ u16 As[128 * 40];
    __shared__ u16 Bs[128 * 40];
    int tid = threadIdx.x;
    int lane = tid & 63, w = tid >> 6;
    int wm = w >> 1, wn = w & 1;
    int row0 = blockIdx.x * 128;
    int n0 = blockIdx.y * 128;
    int lr = tid >> 1;
    int lc = (tid & 1) << 4;

    const f32x4 fz = {0.f, 0.f, 0.f, 0.f};
    f32x4 acc[4][4];
#pragma unroll
    for (int i = 0; i < 4; i++)
#pragma unroll
        for (int j = 0; j < 4; j++) acc[i][j] = fz;

    int kl = (lane >> 4) << 3;
    int l15 = lane & 15;
    int rm = wm * 64 + l15;
    int rn = wn * 64 + l15;

    for (int kb = 0; kb < 8; ++kb) {
        int k0 = kb << 5;
        const u16* pa = WA + ((size_t)(row0 + lr) << 8) + k0 + lc;
        u32x4 a0 = *(const u32x4*)pa;
        u32x4 a1 = *(const u32x4*)(pa + 8);
        const u16* pb = WoT + ((size_t)(n0 + lr) << 8) + k0 + lc;
        u32x4 b0 = *(const u32x4*)pb;
        u32x4 b1 = *(const u32x4*)(pb + 8);
        if (kb) __syncthreads();
        *(u32x4*)&As[lr * 40 + lc] = a0;
        *(u32x4*)&As[lr * 40 + lc + 8] = a1;
        *(u32x4*)&Bs[lr * 40 + lc] = b0;
        *(u32x4*)&Bs[lr * 40 + lc + 8] = b1;
        __syncthreads();
        short8 af[4], bf[4];
#pragma unroll
        for (int i = 0; i < 4; i++) af[i] = *(const short8*)&As[(rm + i * 16) * 40 + kl];
#pragma unroll
        for (int i = 0; i < 4; i++) bf[i] = *(const short8*)&Bs[(rn + i * 16) * 40 + kl];
#pragma unroll
        for (int mi = 0; mi < 4; mi++)
#pragma unroll
            for (int ni = 0; ni < 4; ni++)
                acc[mi][ni] = __builtin_amdgcn_mfma_f32_16x16x32_bf16(af[mi], bf[ni], acc[mi][ni], 0, 0, 0);
    }

#pragma unroll
    for (int mi = 0; mi < 4; mi++)
#pragma unroll
        for (int ni = 0; ni < 4; ni++)
#pragma unroll
            for (int r = 0; r < 4; r++) {
                int row = row0 + wm * 64 + mi * 16 + ((lane >> 4) << 2) + r;
                int col = n0 + wn * 64 + ni * 16 + l15;
                dst[((size_t)row << 8) + col] = acc[mi][ni][r] + ob[col];
            }
}

// ===========================================================================
// ===================== PATH B (small ws) — round-4 code ====================
// ===========================================================================

__global__ __launch_bounds__(256) void transpose_k(
    const float* __restrict__ query_w, const float* __restrict__ key_w,
    const float* __restrict__ value_w, const float* __restrict__ gating_w,
    u16* __restrict__ wt)
{
    int i = blockIdx.x * 256 + threadIdx.x;
    int half = i >> 17;
    int rem = i & 131071;
    int h = rem >> 14, e = rem & 16383;
    int n = e >> 8, k = e & 255;
    int src_idx = k * 256 + h * 32 + (n & 31);
    float v;
    if (half == 0) v = (n < 32) ? key_w[src_idx]   : value_w[src_idx];
    else           v = (n < 32) ? query_w[src_idx] : gating_w[src_idx];
    wt[i] = f2bf(v);
}

__global__ __launch_bounds__(256) void fused_attn_k(
    const float* __restrict__ q_data, const float* __restrict__ m_data,
    const float* __restrict__ bias2, const float* __restrict__ nb,
    const u16* __restrict__ wt, const float* __restrict__ gb,
    u16* __restrict__ WAo)
{
    __shared__ u16 smem[31488];
    u16* Ksh = smem;
    u16* Vt  = smem + 10240;
    u16* Xs  = smem + 18688;
    u16* Wsh = smem + 28928;

    int bid = blockIdx.x;
    int b = bid >> 3, h = bid & 7;
    int tid = threadIdx.x, lane = tid & 63, w = tid >> 6;
    int l15 = lane & 15;
    int kl = (lane >> 4) << 3;
    int rq = (lane >> 4) << 2;
    const f32x4 fz = {0.f, 0.f, 0.f, 0.f};

    float bload[16];
#pragma unroll
    for (int t = 0; t < 16; t++) bload[t] = bias2[(b << 8) + t * 16 + l15];
    float gbc0 = gb[h * 32 + l15];
    float gbc1 = gb[h * 32 + 16 + l15];

    const float* Xg = m_data + ((size_t)b << 16);
    const u16* Wg = wt + (h << 14);
    f32x4 acc[4][4];
#pragma unroll
    for (int i = 0; i < 4; i++)
#pragma unroll
        for (int j = 0; j < 4; j++) acc[i][j] = fz;

    for (int kb = 0; kb < 8; ++kb) {
        Cvt32 am;
        ld32f_bf(Xg + (size_t)tid * 256 + kb * 32, am);
        u32x4 b0, b1;
        int nrow = tid >> 1, nc = (tid & 1) << 4;
        if (tid < 128) {
            const u16* q = Wg + nrow * 256 + kb * 32 + nc;
            b0 = *(const u32x4*)q; b1 = *(const u32x4*)(q + 8);
        }
        if (kb) __syncthreads();
        *(u32x4*)&Xs[tid * 40]      = am.v[0];
        *(u32x4*)&Xs[tid * 40 + 8]  = am.v[1];
        *(u32x4*)&Xs[tid * 40 + 16] = am.v[2];
        *(u32x4*)&Xs[tid * 40 + 24] = am.v[3];
        if (tid < 128) {
            *(u32x4*)&Wsh[nrow * 40 + nc] = b0;
            *(u32x4*)&Wsh[nrow * 40 + nc + 8] = b1;
        }
        __syncthreads();
        short8 af[4], bf[4];
#pragma unroll
        for (int i = 0; i < 4; i++) af[i] = *(const short8*)&Xs[(64 * w + i * 16 + l15) * 40 + kl];
#pragma unroll
        for (int i = 0; i < 4; i++) bf[i] = *(const short8*)&Wsh[(i * 16 + l15) * 40 + kl];
#pragma unroll
        for (int mi = 0; mi < 4; mi++)
#pragma unroll
            for (int ni = 0; ni < 4; ni++)
                acc[mi][ni] = __builtin_amdgcn_mfma_f32_16x16x32_bf16(af[mi], bf[ni], acc[mi][ni], 0, 0, 0);
    }
#pragma unroll
    for (int mi = 0; mi < 4; mi++)
#pragma unroll
        for (int ni = 0; ni < 4; ni++)
#pragma unroll
            for (int r = 0; r < 4; r++) {
                int s = 64 * w + mi * 16 + rq + r;
                int col = ni * 16 + l15;
                u16 v = f2bf(acc[mi][ni][r]);
                if (ni < 2) Ksh[s * 40 + col] = v;
                else        Vt[(col - 32) * 264 + s] = v;
            }
    __syncthreads();

    const float* Xg2 = q_data + ((size_t)b << 16);
    const u16* Wg2 = wt + 131072 + (h << 14);
    f32x4 acc2[4][4];
#pragma unroll
    for (int i = 0; i < 4; i++)
#pragma unroll
        for (int j = 0; j < 4; j++) acc2[i][j] = fz;

    for (int kb = 0; kb < 8; ++kb) {
        Cvt32 am;
        ld32f_bf(Xg2 + (size_t)tid * 256 + kb * 32, am);
        u32x4 b0, b1;
        int nrow = tid >> 1, nc = (tid & 1) << 4;
        if (tid < 128) {
            const u16* q = Wg2 + nrow * 256 + kb * 32 + nc;
            b0 = *(const u32x4*)q; b1 = *(const u32x4*)(q + 8);
        }
        __syncthreads();
        *(u32x4*)&Xs[tid * 40]      = am.v[0];
        *(u32x4*)&Xs[tid * 40 + 8]  = am.v[1];
        *(u32x4*)&Xs[tid * 40 + 16] = am.v[2];
        *(u32x4*)&Xs[tid * 40 + 24] = am.v[3];
        if (tid < 128) {
            *(u32x4*)&Wsh[nrow * 40 + nc] = b0;
            *(u32x4*)&Wsh[nrow * 40 + nc + 8] = b1;
        }
        __syncthreads();
        short8 af[4], bf[4];
#pragma unroll
        for (int i = 0; i < 4; i++) af[i] = *(const short8*)&Xs[(64 * w + i * 16 + l15) * 40 + kl];
#pragma unroll
        for (int i = 0; i < 4; i++) bf[i] = *(const short8*)&Wsh[(i * 16 + l15) * 40 + kl];
#pragma unroll
        for (int mi = 0; mi < 4; mi++)
#pragma unroll
            for (int ni = 0; ni < 4; ni++)
                acc2[mi][ni] = __builtin_amdgcn_mfma_f32_16x16x32_bf16(af[mi], bf[ni], acc2[mi][ni], 0, 0, 0);
    }
    __syncthreads();

    u16* myQ = smem + 18688 + w * 2816;
    u16* myP = myQ + 640;
    const float* nbp = nb + ((size_t)h << 16);
    const float qscale = 0.17677669529663687f;

#pragma unroll
    for (int mt = 0; mt < 4; ++mt) {
#pragma unroll
        for (int ni = 0; ni < 2; ++ni)
#pragma unroll
            for (int r = 0; r < 4; r++)
                myQ[(rq + r) * 40 + ni * 16 + l15] = f2bf(acc2[mt][ni][r] * qscale);

        short8 qf = *(const short8*)&myQ[l15 * 40 + kl];
        f32x4 sc[16];
#pragma unroll
        for (int t = 0; t < 16; t++) {
            short8 kfr = *(const short8*)&Ksh[(t * 16 + l15) * 40 + kl];
            sc[t] = __builtin_amdgcn_mfma_f32_16x16x32_bf16(qf, kfr, fz, 0, 0, 0);
        }

        int q0 = 64 * w + mt * 16 + rq;
        float mrow[4] = {-3e30f, -3e30f, -3e30f, -3e30f};
#pragma unroll
        for (int t = 0; t < 16; t++) {
            int kidx = t * 16 + l15;
#pragma unroll
            for (int r = 0; r < 4; r++) {
                float v = sc[t][r] + bload[t] + nbp[(size_t)(q0 + r) * 256 + kidx];
                sc[t][r] = v;
                mrow[r] = fmaxf(mrow[r], v);
            }
        }
#pragma unroll
        for (int r = 0; r < 4; r++) {
            float m = mrow[r];
            m = fmaxf(m, __shfl_xor(m, 1));
            m = fmaxf(m, __shfl_xor(m, 2));
            m = fmaxf(m, __shfl_xor(m, 4));
            m = fmaxf(m, __shfl_xor(m, 8));
            mrow[r] = m;
        }
        float srow[4] = {0.f, 0.f, 0.f, 0.f};
#pragma unroll
        for (int t = 0; t < 16; t++)
#pragma unroll
            for (int r = 0; r < 4; r++) {
                float p = __expf(sc[t][r] - mrow[r]);
                sc[t][r] = p;
                srow[r] += p;
            }
#pragma unroll
        for (int r = 0; r < 4; r++) {
            float s = srow[r];
            s += __shfl_xor(s, 1);
            s += __shfl_xor(s, 2);
            s += __shfl_xor(s, 4);
            s += __shfl_xor(s, 8);
            srow[r] = 1.f / s;
        }

        f32x4 oacc[2] = {fz, fz};
#pragma unroll
        for (int half = 0; half < 2; ++half) {
#pragma unroll
            for (int t = 0; t < 8; t++)
#pragma unroll
                for (int r = 0; r < 4; r++)
                    myP[(rq + r) * 136 + t * 16 + l15] =
                        f2bf(sc[half * 8 + t][r] * srow[r]);
#pragma unroll
            for (int ks = 0; ks < 4; ++ks) {
                short8 pf = *(const short8*)&myP[l15 * 136 + ks * 32 + kl];
#pragma unroll
                for (int ni = 0; ni < 2; ++ni) {
                    short8 vf = *(const short8*)&Vt[(ni * 16 + l15) * 264 + half * 128 + ks * 32 + kl];
                    oacc[ni] = __builtin_amdgcn_mfma_f32_16x16x32_bf16(pf, vf, oacc[ni], 0, 0, 0);
                }
            }
        }

#pragma unroll
        for (int ni = 0; ni < 2; ++ni) {
            float gbv = ni ? gbc1 : gbc0;
#pragma unroll
            for (int r = 0; r < 4; r++) {
                float gate = 1.f / (1.f + __expf(-(acc2[mt][ni + 2][r] + gbv)));
                size_t idx = (((size_t)b << 8) + q0 + r) * 256 + h * 32 + ni * 16 + l15;
                WAo[idx] = f2bf(oacc[ni][r] * gate);
            }
        }
    }
}

__global__ __launch_bounds__(256) void gemm_out_k(
    const u16* __restrict__ X, const float* __restrict__ Wo,
    float* __restrict__ dst, const float* __restrict__ cbias)
{
    __shared__ u16 As[128 * 40];
    __shared__ u16 Bs[128 * 40];
    int tid = threadIdx.x;
    int lane = tid & 63, w = tid >> 6;
    int wm = w >> 1, wn = w & 1;
    int row0 = blockIdx.x * 128;
    int n0 = blockIdx.y * 128;
    int lr = tid >> 1;
    int lc = (tid & 1) << 4;

    const f32x4 fz = {0.f, 0.f, 0.f, 0.f};
    f32x4 acc[4][4];
#pragma unroll
    for (int i = 0; i < 4; i++)
#pragma unroll
        for (int j = 0; j < 4; j++) acc[i][j] = fz;

    int kl = (lane >> 4) << 3;
    int l15 = lane & 15;
    int rm = wm * 64 + l15;
    int rn = wn * 64 + l15;

    for (int kb = 0; kb < 8; ++kb) {
        int k0 = kb << 5;
        const u16* pa = X + ((size_t)(row0 + lr) << 8) + k0 + lc;
        u32x4 a0 = *(const u32x4*)pa;
        u32x4 a1 = *(const u32x4*)(pa + 8);
        int bk = tid >> 3, bn = (tid & 7) << 4;
        const float* pb = Wo + (size_t)(k0 + bk) * 256 + n0 + bn;
        u16 bu[16];
#pragma unroll
        for (int j = 0; j < 16; j += 4) {
            f32x4 x = *(const f32x4*)(pb + j);
            bu[j] = f2bf(x[0]); bu[j + 1] = f2bf(x[1]);
            bu[j + 2] = f2bf(x[2]); bu[j + 3] = f2bf(x[3]);
        }
        if (kb) __syncthreads();
        *(u32x4*)&As[lr * 40 + lc] = a0;
        *(u32x4*)&As[lr * 40 + lc + 8] = a1;
#pragma unroll
        for (int j = 0; j < 16; j++) Bs[(bn + j) * 40 + bk] = bu[j];
        __syncthreads();
        short8 af[4], bf[4];
#pragma unroll
        for (int i = 0; i < 4; i++) af[i] = *(const short8*)&As[(rm + i * 16) * 40 + kl];
#pragma unroll
        for (int i = 0; i < 4; i++) bf[i] = *(const short8*)&Bs[(rn + i * 16) * 40 + kl];
#pragma unroll
        for (int mi = 0; mi < 4; mi++)
#pragma unroll
            for (int ni = 0; ni < 4; ni++)
                acc[mi][ni] = __builtin_amdgcn_mfma_f32_16x16x32_bf16(af[mi], bf[ni], acc[mi][ni], 0, 0, 0);
    }

#pragma unroll
    for (int mi = 0; mi < 4; mi++)
#pragma unroll
        for (int ni = 0; ni < 4; ni++)
#pragma unroll
            for (int r = 0; r < 4; r++) {
                int row = row0 + wm * 64 + mi * 16 + ((lane >> 4) << 2) + r;
                int col = n0 + wn * 64 + ni * 16 + l15;
                dst[((size_t)row << 8) + col] = acc[mi][ni][r] + cbias[col];
            }
}

// ---------------------------------------------------------------------------
extern "C" void kernel_launch(void* const* d_in, const int* in_sizes, int n_in,
                              void* d_out, int out_size, void* d_ws, size_t ws_size,
                              hipStream_t stream)
{
    const float* q_data   = (const float*)d_in[0];
    const float* m_data   = (const float*)d_in[1];
    const float* bias     = (const float*)d_in[2];
    const float* nb       = (const float*)d_in[3];
    const float* query_w  = (const float*)d_in[4];
    const float* key_w    = (const float*)d_in[5];
    const float* value_w  = (const float*)d_in[6];
    const float* gating_w = (const float*)d_in[7];
    const float* gating_b = (const float*)d_in[8];
    const float* output_w = (const float*)d_in[9];
    const float* output_b = (const float*)d_in[10];

    const size_t NEED_A = 4ull * 33554432 + 524288 + 131072 + 1048576; // 135,921,664

    if (ws_size >= NEED_A) {
        // PATH A — fused projection+attention (no K/V/Q/G HBM round-trip)
        u16* ws   = (u16*)d_ws;
        u16* WA   = ws;                  // 16,777,216 u16 ([65536][256])
        u16* wt   = WA + 16777216;       // 262,144
        u16* WoT  = wt + 262144;         // 65,536
        u16* nbT  = WoT + 65536;         // 524,288  ([h][k][q] * log2e)

        prep_a<<<1408, 256, 0, stream>>>(nb, query_w, key_w, value_w, gating_w,
                                         output_w, wt, WoT, nbT);
        fusedA<<<2048, 256, 0, stream>>>(q_data, m_data, bias, nbT, wt, gating_b, WA);
        gemmout_a<<<dim3(512, 2), 256, 0, stream>>>(WA, WoT, (float*)d_out, output_b);
    } else {
        // PATH B — round-4 proven pipeline
        u16* WAb = (u16*)d_ws;
        u16* wt  = (u16*)d_out;
        transpose_k<<<1024, 256, 0, stream>>>(query_w, key_w, value_w, gating_w, wt);
        fused_attn_k<<<2048, 256, 0, stream>>>(q_data, m_data, bias, nb, wt, gating_b, WAb);
        gemm_out_k<<<dim3(512, 2), 256, 0, stream>>>(WAb, output_w, (float*)d_out, output_b);
    }
}

// Round 13
// 371.572 us; speedup vs baseline: 1.2151x; 1.0009x over previous
//
#include <hip/hip_runtime.h>

typedef unsigned short u16;
typedef __attribute__((ext_vector_type(8))) short short8;
typedef __attribute__((ext_vector_type(4))) float f32x4;
typedef __attribute__((ext_vector_type(4))) unsigned int u32x4;
typedef __attribute__((ext_vector_type(4))) unsigned short u16x4;

#define LOG2E 1.4426950408889634f

__device__ __forceinline__ float bf2f(u16 u) {
    union { float f; unsigned int i; } c; c.i = ((unsigned int)u) << 16; return c.f;
}
__device__ __forceinline__ u16 f2bf(float f) {
    unsigned int x = __float_as_uint(f);
    x += 0x7fff + ((x >> 16) & 1);   // RNE
    return (u16)(x >> 16);
}
// packed f32 pair -> 2x bf16 in one VALU op (RNE, gfx950)
__device__ __forceinline__ unsigned int cvtpk(float lo, float hi) {
    unsigned int d;
    asm("v_cvt_pk_bf16_f32 %0, %1, %2" : "=v"(d) : "v"(lo), "v"(hi));
    return d;
}

union Cvt32 { u32x4 v[4]; u16 u[32]; };

// load 32 consecutive fp32 and convert to 32 bf16 (cvtpk: 16 VALU ops)
__device__ __forceinline__ void ld32f_bf(const float* __restrict__ p, Cvt32& t) {
    union { unsigned int i[8]; u32x4 v[2]; } a;
#pragma unroll
    for (int j = 0; j < 4; j++) {
        f32x4 x = *(const f32x4*)(p + j * 4);
        a.i[j * 2]     = cvtpk(x[0], x[1]);
        a.i[j * 2 + 1] = cvtpk(x[2], x[3]);
    }
    t.v[0] = a.v[0]; t.v[1] = a.v[1];
#pragma unroll
    for (int j = 0; j < 4; j++) {
        f32x4 x = *(const f32x4*)(p + 16 + j * 4);
        a.i[j * 2]     = cvtpk(x[0], x[1]);
        a.i[j * 2 + 1] = cvtpk(x[2], x[3]);
    }
    t.v[2] = a.v[0]; t.v[3] = a.v[1];
}

// ===========================================================================
// ============================ PATH A (large ws) ============================
// ===========================================================================

// Prep: proj weights -> wt (per-head [half][h][n][k] layout, n<32 = K/Q,
// n>=32 = V/G), output_w -> WoT[o][hc], nb -> nbT[h][k][q]*LOG2E bf16.
__global__ __launch_bounds__(256) void prep_a(
    const float* __restrict__ nb,
    const float* __restrict__ qw, const float* __restrict__ kw,
    const float* __restrict__ vw, const float* __restrict__ gw,
    const float* __restrict__ ow,
    u16* __restrict__ wt, u16* __restrict__ WoT, u16* __restrict__ nbT)
{
    __shared__ float tile[64][65];
    int blk = blockIdx.x, tid = threadIdx.x;
    if (blk < 1024) {
        int i = blk * 256 + tid;             // 0..262143
        int half = i >> 17;
        int rem = i & 131071;
        int h = rem >> 14, e = rem & 16383;
        int n = e >> 8, k = e & 255;
        int src_idx = k * 256 + h * 32 + (n & 31);
        float v;
        if (half == 0) v = (n < 32) ? kw[src_idx] : vw[src_idx];
        else           v = (n < 32) ? qw[src_idx] : gw[src_idx];
        wt[i] = f2bf(v);
    } else if (blk < 1280) {
        int e = (blk - 1024) * 256 + tid;    // 0..65535
        int o = e & 255, hc = e >> 8;
        WoT[o * 256 + hc] = f2bf(ow[hc * 256 + o]);
    } else {
        int idx = blk - 1280;                // 0..127
        int q0 = (idx & 3) * 64, k0 = ((idx >> 2) & 3) * 64, h = idx >> 4;
        int rr = tid >> 4;                   // 0..15
        int cc = (tid & 15) << 2;            // 0,4,..,60
        const float* src = nb + ((size_t)(h * 256 + q0)) * 256 + k0;
#pragma unroll
        for (int p = 0; p < 4; p++) {
            int q = rr + p * 16;
            f32x4 x = *(const f32x4*)(src + (size_t)q * 256 + cc);
            tile[q][cc] = x[0]; tile[q][cc + 1] = x[1];
            tile[q][cc + 2] = x[2]; tile[q][cc + 3] = x[3];
        }
        __syncthreads();
        u16* dst = nbT + ((size_t)(h * 256 + k0)) * 256 + q0;
#pragma unroll
        for (int p = 0; p < 4; p++) {
            int k = rr + p * 16;
            u16x4 o;
#pragma unroll
            for (int u = 0; u < 4; u++) o[u] = f2bf(tile[cc + u][k] * LOG2E);
            *(u16x4*)(dst + (size_t)k * 256 + cc) = o;
        }
    }
}

// Fused projection + attention per (b,h). Round-13: myQ/myP ALIASED into
// one per-wave 1152-u16 region (myQ dead once qf is reg-loaded; all
// accesses wave-private + same-pointer so lgkmcnt ordering suffices).
// LDS 51,712 -> 46,592 B: with the ~8KB HW LDS allocation granularity,
// 51,712 rounded to 57,344 -> only 2 blocks/CU (r12 occupancy 22%);
// 46,592 rounds to 49,152 -> 3 blocks/CU. XCD-aware grid swizzle kept
// (r12: FETCH 528->90 MB, confirmed).
__global__ __launch_bounds__(256) void fusedA(
    const float* __restrict__ q_data, const float* __restrict__ m_data,
    const float* __restrict__ bias2, const u16* __restrict__ nbT,
    const u16* __restrict__ wt, const float* __restrict__ gb,
    u16* __restrict__ WA)
{
    __shared__ u16 smem[23296];          // 46,592 B
    u16* Vt  = smem;                     // [32][264]   8,448 u16
    u16* Xs  = smem + 8448;              // [256][40]  10,240 u16 -> becomes Ksh
    u16* Ksh = Xs;                       //   (aliased: K written in-place)
    u16* Wsh = smem + 18688;             // [64][40]    2,560 u16 (proj only)

    int bid = blockIdx.x;
    // XCD-aware swizzle (bijective over 2048): xcd = bid&7 gets b-chunk
    // [32*xcd, 32*xcd+32); same-b h-blocks are 8 consecutive j -> L2-hot.
    int xcd = bid & 7;
    int j = bid >> 3;
    int h = j & 7;
    int b = (xcd << 5) | (j >> 3);
    int tid = threadIdx.x, lane = tid & 63, w = tid >> 6;
    int l15 = lane & 15;
    int kl = (lane >> 4) << 3;
    int rq = (lane >> 4) << 2;
    const f32x4 fz = {0.f, 0.f, 0.f, 0.f};

    float bload[16];
#pragma unroll
    for (int t = 0; t < 16; t++)
        bload[t] = bias2[(b << 8) + t * 16 + l15] * LOG2E;
    float gbc0 = gb[h * 32 + l15];
    float gbc1 = gb[h * 32 + 16 + l15];

    int srow = tid >> 1;                 // 0..127 (staging row within pass)
    int sc16 = (tid & 1) << 4;           // f32 col 0 / 16
    int nrow = tid >> 1, nc = (tid & 1) << 4;

    // ---------- phase 1: Q,G projection (X = q_data[b]) -> acc2 regs --------
    const float* Xg2 = q_data + ((size_t)b << 16);
    const u16* Wg2 = wt + 131072 + (h << 14);
    f32x4 acc2[4][4];
#pragma unroll
    for (int i = 0; i < 4; i++)
#pragma unroll
        for (int j2 = 0; j2 < 4; j2++) acc2[i][j2] = fz;

    for (int kb = 0; kb < 8; ++kb) {
        // coalesced A-stage: 2 passes x (2 thr/row x 128 rows), 64B/thread
        u32x4 c0[2], c1[2];
#pragma unroll
        for (int p = 0; p < 2; ++p) {
            const float* ps = Xg2 + (size_t)(p * 128 + srow) * 256 + kb * 32 + sc16;
            f32x4 x0 = *(const f32x4*)ps;
            f32x4 x1 = *(const f32x4*)(ps + 4);
            f32x4 x2 = *(const f32x4*)(ps + 8);
            f32x4 x3 = *(const f32x4*)(ps + 12);
            union { unsigned int i4[4]; u32x4 v; } a, c;
            a.i4[0] = cvtpk(x0[0], x0[1]); a.i4[1] = cvtpk(x0[2], x0[3]);
            a.i4[2] = cvtpk(x1[0], x1[1]); a.i4[3] = cvtpk(x1[2], x1[3]);
            c.i4[0] = cvtpk(x2[0], x2[1]); c.i4[1] = cvtpk(x2[2], x2[3]);
            c.i4[2] = cvtpk(x3[0], x3[1]); c.i4[3] = cvtpk(x3[2], x3[3]);
            c0[p] = a.v; c1[p] = c.v;
        }
        u32x4 b0, b1;
        if (tid < 128) {
            const u16* q = Wg2 + nrow * 256 + kb * 32 + nc;
            b0 = *(const u32x4*)q; b1 = *(const u32x4*)(q + 8);
        }
        if (kb) __syncthreads();
#pragma unroll
        for (int p = 0; p < 2; ++p) {
            int row = p * 128 + srow;
            *(u32x4*)&Xs[row * 40 + sc16]     = c0[p];
            *(u32x4*)&Xs[row * 40 + sc16 + 8] = c1[p];
        }
        if (tid < 128) {
            *(u32x4*)&Wsh[nrow * 40 + nc] = b0;
            *(u32x4*)&Wsh[nrow * 40 + nc + 8] = b1;
        }
        __syncthreads();
        short8 af[4], bf[4];
#pragma unroll
        for (int i = 0; i < 4; i++) af[i] = *(const short8*)&Xs[(64 * w + i * 16 + l15) * 40 + kl];
#pragma unroll
        for (int i = 0; i < 4; i++) bf[i] = *(const short8*)&Wsh[(i * 16 + l15) * 40 + kl];
#pragma unroll
        for (int mi = 0; mi < 4; mi++)
#pragma unroll
            for (int ni = 0; ni < 4; ni++)
                acc2[mi][ni] = __builtin_amdgcn_mfma_f32_16x16x32_bf16(af[mi], bf[ni], acc2[mi][ni], 0, 0, 0);
    }

    // ---------- phase 2: K,V projection (X = m_data[b]) -> Ksh(=Xs), Vt -----
    const float* Xg = m_data + ((size_t)b << 16);
    const u16* Wg = wt + (h << 14);
    f32x4 acc[4][4];
#pragma unroll
    for (int i = 0; i < 4; i++)
#pragma unroll
        for (int j2 = 0; j2 < 4; j2++) acc[i][j2] = fz;

    for (int kb = 0; kb < 8; ++kb) {
        u32x4 c0[2], c1[2];
#pragma unroll
        for (int p = 0; p < 2; ++p) {
            const float* ps = Xg + (size_t)(p * 128 + srow) * 256 + kb * 32 + sc16;
            f32x4 x0 = *(const f32x4*)ps;
            f32x4 x1 = *(const f32x4*)(ps + 4);
            f32x4 x2 = *(const f32x4*)(ps + 8);
            f32x4 x3 = *(const f32x4*)(ps + 12);
            union { unsigned int i4[4]; u32x4 v; } a, c;
            a.i4[0] = cvtpk(x0[0], x0[1]); a.i4[1] = cvtpk(x0[2], x0[3]);
            a.i4[2] = cvtpk(x1[0], x1[1]); a.i4[3] = cvtpk(x1[2], x1[3]);
            c.i4[0] = cvtpk(x2[0], x2[1]); c.i4[1] = cvtpk(x2[2], x2[3]);
            c.i4[2] = cvtpk(x3[0], x3[1]); c.i4[3] = cvtpk(x3[2], x3[3]);
            c0[p] = a.v; c1[p] = c.v;
        }
        u32x4 b0, b1;
        if (tid < 128) {
            const u16* q = Wg + nrow * 256 + kb * 32 + nc;
            b0 = *(const u32x4*)q; b1 = *(const u32x4*)(q + 8);
        }
        __syncthreads();   // unconditional: protects phase-1 reads at kb=0
#pragma unroll
        for (int p = 0; p < 2; ++p) {
            int row = p * 128 + srow;
            *(u32x4*)&Xs[row * 40 + sc16]     = c0[p];
            *(u32x4*)&Xs[row * 40 + sc16 + 8] = c1[p];
        }
        if (tid < 128) {
            *(u32x4*)&Wsh[nrow * 40 + nc] = b0;
            *(u32x4*)&Wsh[nrow * 40 + nc + 8] = b1;
        }
        __syncthreads();
        short8 af[4], bf[4];
#pragma unroll
        for (int i = 0; i < 4; i++) af[i] = *(const short8*)&Xs[(64 * w + i * 16 + l15) * 40 + kl];
#pragma unroll
        for (int i = 0; i < 4; i++) bf[i] = *(const short8*)&Wsh[(i * 16 + l15) * 40 + kl];
#pragma unroll
        for (int mi = 0; mi < 4; mi++)
#pragma unroll
            for (int ni = 0; ni < 4; ni++)
                acc[mi][ni] = __builtin_amdgcn_mfma_f32_16x16x32_bf16(af[mi], bf[ni], acc[mi][ni], 0, 0, 0);
    }
    // epilogue: K into Ksh (in-place over this wave's own Xs band), V -> Vt
#pragma unroll
    for (int mi = 0; mi < 4; mi++)
#pragma unroll
        for (int ni = 0; ni < 4; ni++)
#pragma unroll
            for (int r = 0; r < 4; r++) {
                int s = 64 * w + mi * 16 + rq + r;
                int col = ni * 16 + l15;
                u16 v = f2bf(acc[mi][ni][r]);
                if (ni < 2) Ksh[s * 40 + col] = v;
                else        Vt[(col - 32) * 264 + s] = v;
            }
    __syncthreads();

    // ---------- phase 3: attention (fully unrolled mt — static acc2 idx) ----
    // myQ and myP ALIASED: myQ ([16][40]) is dead once qf is in registers,
    // so myP ([16][72]) reuses the same per-wave region (1152 u16/wave).
    // Wave-private + same-pointer accesses -> lgkmcnt ordering is enough.
    u16* myQP = smem + 18688 + w * 1152;
    const u16* nbh = nbT + ((size_t)h << 16);
    const float qs = 0.17677669529663687f * LOG2E;
    int orow = lane >> 2, ocol = (lane & 3) << 3;

#pragma unroll
    for (int mt = 0; mt < 4; ++mt) {
        int q0 = 64 * w + mt * 16 + rq;
#pragma unroll
        for (int ni = 0; ni < 2; ++ni)
#pragma unroll
            for (int r = 0; r < 4; r++)
                myQP[(rq + r) * 40 + ni * 16 + l15] = f2bf(acc2[mt][ni][r] * qs);
        short8 qf = *(const short8*)&myQP[l15 * 40 + kl];

        const u16* nbp = nbh + q0;
        float srow_[4] = {0.f, 0.f, 0.f, 0.f};
        f32x4 oacc[2] = {fz, fz};
#pragma unroll
        for (int qt = 0; qt < 4; ++qt) {
            f32x4 sc[4];
#pragma unroll
            for (int t = 0; t < 4; t++) {
                int tt = qt * 4 + t;
                short8 kfr = *(const short8*)&Ksh[(tt * 16 + l15) * 40 + kl];
                f32x4 cb = {bload[tt], bload[tt], bload[tt], bload[tt]};
                sc[t] = __builtin_amdgcn_mfma_f32_16x16x32_bf16(qf, kfr, cb, 0, 0, 0);
            }
#pragma unroll
            for (int t = 0; t < 4; t++) {
                int tt = qt * 4 + t;
                u16x4 nbv = *(const u16x4*)(nbp + ((tt * 16 + l15) << 8));
#pragma unroll
                for (int r = 0; r < 4; r++) {
                    // no-max softmax in exp2 domain (|logit*log2e| << 127)
                    float p = __builtin_amdgcn_exp2f(sc[t][r] + bf2f(nbv[r]));
                    srow_[r] += p;
                    myQP[(rq + r) * 72 + t * 16 + l15] = f2bf(p);
                }
            }
#pragma unroll
            for (int ks = 0; ks < 2; ++ks) {
                short8 pf = *(const short8*)&myQP[l15 * 72 + ks * 32 + kl];
#pragma unroll
                for (int ni = 0; ni < 2; ++ni) {
                    short8 vf = *(const short8*)&Vt[(ni * 16 + l15) * 264 + qt * 64 + ks * 32 + kl];
                    oacc[ni] = __builtin_amdgcn_mfma_f32_16x16x32_bf16(pf, vf, oacc[ni], 0, 0, 0);
                }
            }
        }
#pragma unroll
        for (int r = 0; r < 4; r++) {
            float s = srow_[r];
            s += __shfl_xor(s, 1);
            s += __shfl_xor(s, 2);
            s += __shfl_xor(s, 4);
            s += __shfl_xor(s, 8);
            srow_[r] = __builtin_amdgcn_rcpf(s);
        }

        // gate from live acc2 (static mt), normalize, stage
#pragma unroll
        for (int ni = 0; ni < 2; ++ni) {
            float gbv = ni ? gbc1 : gbc0;
#pragma unroll
            for (int r = 0; r < 4; r++) {
                float gate = __builtin_amdgcn_rcpf(
                    1.f + __builtin_amdgcn_exp2f(-(acc2[mt][ni + 2][r] + gbv) * LOG2E));
                myQP[(rq + r) * 40 + ni * 16 + l15] = f2bf(oacc[ni][r] * srow_[r] * gate);
            }
        }
        // coalesced store: WA[(b*256+q)][h*32+c], 16B/lane
        u32x4 ov = *(const u32x4*)&myQP[orow * 40 + ocol];
        *(u32x4*)(WA + ((size_t)((b << 8) + 64 * w + mt * 16 + orow) << 8) + h * 32 + ocol) = ov;
    }
}

// Output GEMM: out[65536,256] = WA[65536,256](bf16) @ WoT^T + output_b.
// Round-13: 1-D grid + XCD-pairing swizzle — the two n-halves sharing an
// A-tile run adjacently on one XCD, and x-range [64*xcd, 64*xcd+64) covers
// exactly the WA rows that fusedA produced ON THAT XCD (b in
// [32*xcd, 32*xcd+32)) -> A-reads hit the writer's still-resident L2.
__global__ __launch_bounds__(256) void gemmout_a(
    const u16* __restrict__ WA, const u16* __restrict__ WoT,
    float* __restrict__ dst, const float* __restrict__ ob)
{
    __shared__ u16 As[128 * 40];
    __shared__ u16 Bs[128 * 40];
    int bid = blockIdx.x;               // 0..1023
    int xcd = bid & 7;
    int s = bid >> 3;
    int y = s & 1;
    int x = (xcd << 6) | (s >> 1);      // 0..511
    int row0 = x * 128;
    int n0 = y * 128;

    int tid = threadIdx.x;
    int lane = tid & 63, w = tid >> 6;
    int wm = w >> 1, wn = w & 1;
    int lr = tid >> 1;
    int lc = (tid & 1) << 4;

    const f32x4 fz = {0.f, 0.f, 0.f, 0.f};
    f32x4 acc[4][4];
#pragma unroll
    for (int i = 0; i < 4; i++)
#pragma unroll
        for (int j = 0; j < 4; j++) acc[i][j] = fz;

    int kl = (lane >> 4) << 3;
    int l15 = lane & 15;
    int rm = wm * 64 + l15;
    int rn = wn * 64 + l15;

    for (int kb = 0; kb < 8; ++kb) {
        int k0 = kb << 5;
        const u16* pa = WA + ((size_t)(row0 + lr) << 8) + k0 + lc;
        u32x4 a0 = *(const u32x4*)pa;
        u32x4 a1 = *(const u32x4*)(pa + 8);
        const u16* pb = WoT + ((size_t)(n0 + lr) << 8) + k0 + lc;
        u32x4 b0 = *(const u32x4*)pb;
        u32x4 b1 = *(const u32x4*)(pb + 8);
        if (kb) __syncthreads();
        *(u32x4*)&As[lr * 40 + lc] = a0;
        *(u32x4*)&As[lr * 40 + lc + 8] = a1;
        *(u32x4*)&Bs[lr * 40 + lc] = b0;
        *(u32x4*)&Bs[lr * 40 + lc + 8] = b1;
        __syncthreads();
        short8 af[4], bf[4];
#pragma unroll
        for (int i = 0; i < 4; i++) af[i] = *(const short8*)&As[(rm + i * 16) * 40 + kl];
#pragma unroll
        for (int i = 0; i < 4; i++) bf[i] = *(const short8*)&Bs[(rn + i * 16) * 40 + kl];
#pragma unroll
        for (int mi = 0; mi < 4; mi++)
#pragma unroll
            for (int ni = 0; ni < 4; ni++)
                acc[mi][ni] = __builtin_amdgcn_mfma_f32_16x16x32_bf16(af[mi], bf[ni], acc[mi][ni], 0, 0, 0);
    }

#pragma unroll
    for (int mi = 0; mi < 4; mi++)
#pragma unroll
        for (int ni = 0; ni < 4; ni++)
#pragma unroll
            for (int r = 0; r < 4; r++) {
                int row = row0 + wm * 64 + mi * 16 + ((lane >> 4) << 2) + r;
                int col = n0 + wn * 64 + ni * 16 + l15;
                dst[((size_t)row << 8) + col] = acc[mi][ni][r] + ob[col];
            }
}

// ===========================================================================
// ===================== PATH B (small ws) — round-4 code ====================
// ===========================================================================

__global__ __launch_bounds__(256) void transpose_k(
    const float* __restrict__ query_w, const float* __restrict__ key_w,
    const float* __restrict__ value_w, const float* __restrict__ gating_w,
    u16* __restrict__ wt)
{
    int i = blockIdx.x * 256 + threadIdx.x;
    int half = i >> 17;
    int rem = i & 131071;
    int h = rem >> 14, e = rem & 16383;
    int n = e >> 8, k = e & 255;
    int src_idx = k * 256 + h * 32 + (n & 31);
    float v;
    if (half == 0) v = (n < 32) ? key_w[src_idx]   : value_w[src_idx];
    else           v = (n < 32) ? query_w[src_idx] : gating_w[src_idx];
    wt[i] = f2bf(v);
}

__global__ __launch_bounds__(256) void fused_attn_k(
    const float* __restrict__ q_data, const float* __restrict__ m_data,
    const float* __restrict__ bias2, const float* __restrict__ nb,
    const u16* __restrict__ wt, const float* __restrict__ gb,
    u16* __restrict__ WAo)
{
    __shared__ u16 smem[31488];
    u16* Ksh = smem;
    u16* Vt  = smem + 10240;
    u16* Xs  = smem + 18688;
    u16* Wsh = smem + 28928;

    int bid = blockIdx.x;
    int b = bid >> 3, h = bid & 7;
    int tid = threadIdx.x, lane = tid & 63, w = tid >> 6;
    int l15 = lane & 15;
    int kl = (lane >> 4) << 3;
    int rq = (lane >> 4) << 2;
    const f32x4 fz = {0.f, 0.f, 0.f, 0.f};

    float bload[16];
#pragma unroll
    for (int t = 0; t < 16; t++) bload[t] = bias2[(b << 8) + t * 16 + l15];
    float gbc0 = gb[h * 32 + l15];
    float gbc1 = gb[h * 32 + 16 + l15];

    const float* Xg = m_data + ((size_t)b << 16);
    const u16* Wg = wt + (h << 14);
    f32x4 acc[4][4];
#pragma unroll
    for (int i = 0; i < 4; i++)
#pragma unroll
        for (int j = 0; j < 4; j++) acc[i][j] = fz;

    for (int kb = 0; kb < 8; ++kb) {
        Cvt32 am;
        ld32f_bf(Xg + (size_t)tid * 256 + kb * 32, am);
        u32x4 b0, b1;
        int nrow = tid >> 1, nc = (tid & 1) << 4;
        if (tid < 128) {
            const u16* q = Wg + nrow * 256 + kb * 32 + nc;
            b0 = *(const u32x4*)q; b1 = *(const u32x4*)(q + 8);
        }
        if (kb) __syncthreads();
        *(u32x4*)&Xs[tid * 40]      = am.v[0];
        *(u32x4*)&Xs[tid * 40 + 8]  = am.v[1];
        *(u32x4*)&Xs[tid * 40 + 16] = am.v[2];
        *(u32x4*)&Xs[tid * 40 + 24] = am.v[3];
        if (tid < 128) {
            *(u32x4*)&Wsh[nrow * 40 + nc] = b0;
            *(u32x4*)&Wsh[nrow * 40 + nc + 8] = b1;
        }
        __syncthreads();
        short8 af[4], bf[4];
#pragma unroll
        for (int i = 0; i < 4; i++) af[i] = *(const short8*)&Xs[(64 * w + i * 16 + l15) * 40 + kl];
#pragma unroll
        for (int i = 0; i < 4; i++) bf[i] = *(const short8*)&Wsh[(i * 16 + l15) * 40 + kl];
#pragma unroll
        for (int mi = 0; mi < 4; mi++)
#pragma unroll
            for (int ni = 0; ni < 4; ni++)
                acc[mi][ni] = __builtin_amdgcn_mfma_f32_16x16x32_bf16(af[mi], bf[ni], acc[mi][ni], 0, 0, 0);
    }
#pragma unroll
    for (int mi = 0; mi < 4; mi++)
#pragma unroll
        for (int ni = 0; ni < 4; ni++)
#pragma unroll
            for (int r = 0; r < 4; r++) {
                int s = 64 * w + mi * 16 + rq + r;
                int col = ni * 16 + l15;
                u16 v = f2bf(acc[mi][ni][r]);
                if (ni < 2) Ksh[s * 40 + col] = v;
                else        Vt[(col - 32) * 264 + s] = v;
            }
    __syncthreads();

    const float* Xg2 = q_data + ((size_t)b << 16);
    const u16* Wg2 = wt + 131072 + (h << 14);
    f32x4 acc2[4][4];
#pragma unroll
    for (int i = 0; i < 4; i++)
#pragma unroll
        for (int j = 0; j < 4; j++) acc2[i][j] = fz;

    for (int kb = 0; kb < 8; ++kb) {
        Cvt32 am;
        ld32f_bf(Xg2 + (size_t)tid * 256 + kb * 32, am);
        u32x4 b0, b1;
        int nrow = tid >> 1, nc = (tid & 1) << 4;
        if (tid < 128) {
            const u16* q = Wg2 + nrow * 256 + kb * 32 + nc;
            b0 = *(const u32x4*)q; b1 = *(const u32x4*)(q + 8);
        }
        __syncthreads();
        *(u32x4*)&Xs[tid * 40]      = am.v[0];
        *(u32x4*)&Xs[tid * 40 + 8]  = am.v[1];
        *(u32x4*)&Xs[tid * 40 + 16] = am.v[2];
        *(u32x4*)&Xs[tid * 40 + 24] = am.v[3];
        if (tid < 128) {
            *(u32x4*)&Wsh[nrow * 40 + nc] = b0;
            *(u32x4*)&Wsh[nrow * 40 + nc + 8] = b1;
        }
        __syncthreads();
        short8 af[4], bf[4];
#pragma unroll
        for (int i = 0; i < 4; i++) af[i] = *(const short8*)&Xs[(64 * w + i * 16 + l15) * 40 + kl];
#pragma unroll
        for (int i = 0; i < 4; i++) bf[i] = *(const short8*)&Wsh[(i * 16 + l15) * 40 + kl];
#pragma unroll
        for (int mi = 0; mi < 4; mi++)
#pragma unroll
            for (int ni = 0; ni < 4; ni++)
                acc2[mi][ni] = __builtin_amdgcn_mfma_f32_16x16x32_bf16(af[mi], bf[ni], acc2[mi][ni], 0, 0, 0);
    }
    __syncthreads();

    u16* myQ = smem + 18688 + w * 2816;
    u16* myP = myQ + 640;
    const float* nbp = nb + ((size_t)h << 16);
    const float qscale = 0.17677669529663687f;

#pragma unroll
    for (int mt = 0; mt < 4; ++mt) {
#pragma unroll
        for (int ni = 0; ni < 2; ++ni)
#pragma unroll
            for (int r = 0; r < 4; r++)
                myQ[(rq + r) * 40 + ni * 16 + l15] = f2bf(acc2[mt][ni][r] * qscale);

        short8 qf = *(const short8*)&myQ[l15 * 40 + kl];
        f32x4 sc[16];
#pragma unroll
        for (int t = 0; t < 16; t++) {
            short8 kfr = *(const short8*)&Ksh[(t * 16 + l15) * 40 + kl];
            sc[t] = __builtin_amdgcn_mfma_f32_16x16x32_bf16(qf, kfr, fz, 0, 0, 0);
        }

        int q0 = 64 * w + mt * 16 + rq;
        float mrow[4] = {-3e30f, -3e30f, -3e30f, -3e30f};
#pragma unroll
        for (int t = 0; t < 16; t++) {
            int kidx = t * 16 + l15;
#pragma unroll
            for (int r = 0; r < 4; r++) {
                float v = sc[t][r] + bload[t] + nbp[(size_t)(q0 + r) * 256 + kidx];
                sc[t][r] = v;
                mrow[r] = fmaxf(mrow[r], v);
            }
        }
#pragma unroll
        for (int r = 0; r < 4; r++) {
            float m = mrow[r];
            m = fmaxf(m, __shfl_xor(m, 1));
            m = fmaxf(m, __shfl_xor(m, 2));
            m = fmaxf(m, __shfl_xor(m, 4));
            m = fmaxf(m, __shfl_xor(m, 8));
            mrow[r] = m;
        }
        float srow[4] = {0.f, 0.f, 0.f, 0.f};
#pragma unroll
        for (int t = 0; t < 16; t++)
#pragma unroll
            for (int r = 0; r < 4; r++) {
                float p = __expf(sc[t][r] - mrow[r]);
                sc[t][r] = p;
                srow[r] += p;
            }
#pragma unroll
        for (int r = 0; r < 4; r++) {
            float s = srow[r];
            s += __shfl_xor(s, 1);
            s += __shfl_xor(s, 2);
            s += __shfl_xor(s, 4);
            s += __shfl_xor(s, 8);
            srow[r] = 1.f / s;
        }

        f32x4 oacc[2] = {fz, fz};
#pragma unroll
        for (int half = 0; half < 2; ++half) {
#pragma unroll
            for (int t = 0; t < 8; t++)
#pragma unroll
                for (int r = 0; r < 4; r++)
                    myP[(rq + r) * 136 + t * 16 + l15] =
                        f2bf(sc[half * 8 + t][r] * srow[r]);
#pragma unroll
            for (int ks = 0; ks < 4; ++ks) {
                short8 pf = *(const short8*)&myP[l15 * 136 + ks * 32 + kl];
#pragma unroll
                for (int ni = 0; ni < 2; ++ni) {
                    short8 vf = *(const short8*)&Vt[(ni * 16 + l15) * 264 + half * 128 + ks * 32 + kl];
                    oacc[ni] = __builtin_amdgcn_mfma_f32_16x16x32_bf16(pf, vf, oacc[ni], 0, 0, 0);
                }
            }
        }

#pragma unroll
        for (int ni = 0; ni < 2; ++ni) {
            float gbv = ni ? gbc1 : gbc0;
#pragma unroll
            for (int r = 0; r < 4; r++) {
                float gate = 1.f / (1.f + __expf(-(acc2[mt][ni + 2][r] + gbv)));
                size_t idx = (((size_t)b << 8) + q0 + r) * 256 + h * 32 + ni * 16 + l15;
                WAo[idx] = f2bf(oacc[ni][r] * gate);
            }
        }
    }
}

__global__ __launch_bounds__(256) void gemm_out_k(
    const u16* __restrict__ X, const float* __restrict__ Wo,
    float* __restrict__ dst, const float* __restrict__ cbias)
{
    __shared__ u16 As[128 * 40];
    __shared__ u16 Bs[128 * 40];
    int tid = threadIdx.x;
    int lane = tid & 63, w = tid >> 6;
    int wm = w >> 1, wn = w & 1;
    int row0 = blockIdx.x * 128;
    int n0 = blockIdx.y * 128;
    int lr = tid >> 1;
    int lc = (tid & 1) << 4;

    const f32x4 fz = {0.f, 0.f, 0.f, 0.f};
    f32x4 acc[4][4];
#pragma unroll
    for (int i = 0; i < 4; i++)
#pragma unroll
        for (int j = 0; j < 4; j++) acc[i][j] = fz;

    int kl = (lane >> 4) << 3;
    int l15 = lane & 15;
    int rm = wm * 64 + l15;
    int rn = wn * 64 + l15;

    for (int kb = 0; kb < 8; ++kb) {
        int k0 = kb << 5;
        const u16* pa = X + ((size_t)(row0 + lr) << 8) + k0 + lc;
        u32x4 a0 = *(const u32x4*)pa;
        u32x4 a1 = *(const u32x4*)(pa + 8);
        int bk = tid >> 3, bn = (tid & 7) << 4;
        const float* pb = Wo + (size_t)(k0 + bk) * 256 + n0 + bn;
        u16 bu[16];
#pragma unroll
        for (int j = 0; j < 16; j += 4) {
            f32x4 x = *(const f32x4*)(pb + j);
            bu[j] = f2bf(x[0]); bu[j + 1] = f2bf(x[1]);
            bu[j + 2] = f2bf(x[2]); bu[j + 3] = f2bf(x[3]);
        }
        if (kb) __syncthreads();
        *(u32x4*)&As[lr * 40 + lc] = a0;
        *(u32x4*)&As[lr * 40 + lc + 8] = a1;
#pragma unroll
        for (int j = 0; j < 16; j++) Bs[(bn + j) * 40 + bk] = bu[j];
        __syncthreads();
        short8 af[4], bf[4];
#pragma unroll
        for (int i = 0; i < 4; i++) af[i] = *(const short8*)&As[(rm + i * 16) * 40 + kl];
#pragma unroll
        for (int i = 0; i < 4; i++) bf[i] = *(const short8*)&Bs[(rn + i * 16) * 40 + kl];
#pragma unroll
        for (int mi = 0; mi < 4; mi++)
#pragma unroll
            for (int ni = 0; ni < 4; ni++)
                acc[mi][ni] = __builtin_amdgcn_mfma_f32_16x16x32_bf16(af[mi], bf[ni], acc[mi][ni], 0, 0, 0);
    }

#pragma unroll
    for (int mi = 0; mi < 4; mi++)
#pragma unroll
        for (int ni = 0; ni < 4; ni++)
#pragma unroll
            for (int r = 0; r < 4; r++) {
                int row = row0 + wm * 64 + mi * 16 + ((lane >> 4) << 2) + r;
                int col = n0 + wn * 64 + ni * 16 + l15;
                dst[((size_t)row << 8) + col] = acc[mi][ni][r] + cbias[col];
            }
}

// ---------------------------------------------------------------------------
extern "C" void kernel_launch(void* const* d_in, const int* in_sizes, int n_in,
                              void* d_out, int out_size, void* d_ws, size_t ws_size,
                              hipStream_t stream)
{
    const float* q_data   = (const float*)d_in[0];
    const float* m_data   = (const float*)d_in[1];
    const float* bias     = (const float*)d_in[2];
    const float* nb       = (const float*)d_in[3];
    const float* query_w  = (const float*)d_in[4];
    const float* key_w    = (const float*)d_in[5];
    const float* value_w  = (const float*)d_in[6];
    const float* gating_w = (const float*)d_in[7];
    const float* gating_b = (const float*)d_in[8];
    const float* output_w = (const float*)d_in[9];
    const float* output_b = (const float*)d_in[10];

    const size_t NEED_A = 4ull * 33554432 + 524288 + 131072 + 1048576; // 135,921,664

    if (ws_size >= NEED_A) {
        // PATH A — fused projection+attention (no K/V/Q/G HBM round-trip)
        u16* ws   = (u16*)d_ws;
        u16* WA   = ws;                  // 16,777,216 u16 ([65536][256])
        u16* wt   = WA + 16777216;       // 262,144
        u16* WoT  = wt + 262144;         // 65,536
        u16* nbT  = WoT + 65536;         // 524,288  ([h][k][q] * log2e)

        prep_a<<<1408, 256, 0, stream>>>(nb, query_w, key_w, value_w, gating_w,
                                         output_w, wt, WoT, nbT);
        fusedA<<<2048, 256, 0, stream>>>(q_data, m_data, bias, nbT, wt, gating_b, WA);
        gemmout_a<<<1024, 256, 0, stream>>>(WA, WoT, (float*)d_out, output_b);
    } else {
        // PATH B — round-4 proven pipeline
        u16* WAb = (u16*)d_ws;
        u16* wt  = (u16*)d_out;
        transpose_k<<<1024, 256, 0, stream>>>(query_w, key_w, value_w, gating_w, wt);
        fused_attn_k<<<2048, 256, 0, stream>>>(q_data, m_data, bias, nb, wt, gating_b, WAb);
        gemm_out_k<<<dim3(512, 2), 256, 0, stream>>>(WAb, output_w, (float*)d_out, output_b);
    }
}